// Round 13
// baseline (523.289 us; speedup 1.0000x reference)
//
#include <hip/hip_runtime.h>
#include <hip/hip_bf16.h>
#include <math.h>

typedef __attribute__((ext_vector_type(8))) unsigned short ushort8;
typedef __attribute__((ext_vector_type(8))) short short8;
typedef __attribute__((ext_vector_type(4))) float f32x4;
typedef __attribute__((ext_vector_type(4))) unsigned short ushort4v;
typedef __attribute__((ext_vector_type(4))) int i32x4;
typedef unsigned int u32;

namespace {
constexpr int B = 16, L0 = 512, L1 = 256, NS = 32, D = 256, H = 8, NL = 4, HM = 4;
constexpr int T = L0 + L1 + NS + 1;   // 801
constexpr int HD = D / H;             // 32
constexpr int NS_S = L0 + L1;         // 768
constexpr int TPAD = 832;             // 13*64 (fixed per-bh K/V stride)
constexpr int ROWP = 13312;           // 16*832 compact-row capacity
constexpr float EPS = 1e-5f;
constexpr float SCL2  = 0.17677669529663687f * 1.4426950408889634f;  // SCALE*log2e
}

__device__ __forceinline__ ushort f2bf(float f) {
    union { float f; unsigned u; } v; v.f = f;
    return (ushort)((v.u + 0x7fffu + ((v.u >> 16) & 1u)) >> 16);
}

__device__ __forceinline__ u32 cvtpk(float a, float b) {
    u32 r;
    asm("v_cvt_pk_bf16_f32 %0, %1, %2" : "=v"(r) : "v"(a), "v"(b));
    return r;
}

__device__ __forceinline__ void gload_lds16(const void* g, void* l) {
    __builtin_amdgcn_global_load_lds(
        (const __attribute__((address_space(1))) u32*)g,
        (__attribute__((address_space(3))) u32*)l, 16, 0, 0);
}

// compact-row prefix: offset of batch b (64-aligned caps); b=16 -> total rows
__device__ __forceinline__ int offs_of(const int* __restrict__ l0,
                                       const int* __restrict__ l1, int b) {
    int acc = 0;
    for (int j = 0; j < b; ++j) acc += ((l0[j] + l1[j] + 96) >> 6) << 6;
    return acc;
}

// ---------------- unified weight prep: all four W[K][N] f32 -> W^T[N][K] bf16 ----------------
__global__ __launch_bounds__(256) void k_wprep_all(
    const float* __restrict__ qkvw, const float* __restrict__ outw,
    const float* __restrict__ f1w, const float* __restrict__ f2w,
    ushort* __restrict__ qkvt, ushort* __restrict__ outt,
    ushort* __restrict__ f1t, ushort* __restrict__ f2t)
{
    int id = blockIdx.x;
    const float* src; ushort* dst; int K, N;
    if (id < 768)        { src = qkvw; dst = qkvt; K = 256;  N = 768;  }
    else if (id < 1024)  { id -= 768;  src = outw; dst = outt; K = 256; N = 256; }
    else if (id < 2048)  { id -= 1024; src = f1w;  dst = f1t;  K = 256; N = 1024; }
    else                 { id -= 2048; src = f2w;  dst = f2t;  K = 1024; N = 256; }
    const int ktiles = K >> 5, per = ktiles * (N >> 5);
    const int layer = id / per, rem = id % per;
    const int kb = (rem % ktiles) * 32, nb = (rem / ktiles) * 32;
    src += (size_t)layer * K * N; dst += (size_t)layer * K * N;

    __shared__ float t[32][33];
    const int c = threadIdx.x & 31, r8 = threadIdx.x >> 5;
#pragma unroll
    for (int rr = 0; rr < 32; rr += 8)
        t[r8 + rr][c] = src[(size_t)(kb + r8 + rr) * N + nb + c];
    __syncthreads();
#pragma unroll
    for (int rr = 0; rr < 32; rr += 8)
        dst[(size_t)(nb + r8 + rr) * K + kb + c] = f2bf(t[c][r8 + rr]);
}

// ---------------- build compact x + first LN1 fused; padding rows zeroed ----------------
__global__ __launch_bounds__(256) void k_build_ln(
    const float* __restrict__ s0, const float* __restrict__ s1,
    const float* __restrict__ ns, const float* __restrict__ dom,
    const float* __restrict__ cls, const float* __restrict__ lnw,
    const float* __restrict__ lnb, const int* __restrict__ len0,
    const int* __restrict__ len1, float* __restrict__ x, ushort* __restrict__ xn)
{
    const int wid = threadIdx.x >> 6, lane = threadIdx.x & 63;
    const int row = blockIdx.x * 4 + wid;
    if (row >= ROWP) return;
    const int d0 = lane * 4;

    int bsel = -1, t = -1, acc = 0;
    for (int j = 0; j < 16; ++j) {
        const int n0 = len0[j], n1 = len1[j];
        const int nvj = n0 + n1 + 33;
        const int cap = ((nvj + 63) >> 6) << 6;
        if (row < acc + cap) {
            const int loc = row - acc;
            if (loc < nvj)
                t = (loc < n0) ? loc
                  : (loc < n0 + n1) ? (L0 + loc - n0)
                  : (NS_S + loc - n0 - n1);
            bsel = j;
            break;
        }
        acc += cap;
    }
    if (bsel < 0 || t < 0) {
        float4 z = {0.f, 0.f, 0.f, 0.f};
        *(float4*)(x + (size_t)row * D + d0) = z;
        ushort4v z4 = {0, 0, 0, 0};
        *(ushort4v*)(xn + (size_t)row * D + d0) = z4;
        return;
    }
    const int b = bsel;
    float4 v;
    if (t < L0) {
        v = *(const float4*)(s0 + ((size_t)b * L0 + t) * D + d0);
        float4 dm = *(const float4*)(dom + d0);
        v.x += dm.x; v.y += dm.y; v.z += dm.z; v.w += dm.w;
    } else if (t < NS_S) {
        v = *(const float4*)(s1 + ((size_t)b * L1 + (t - L0)) * D + d0);
        float4 dm = *(const float4*)(dom + D + d0);
        v.x += dm.x; v.y += dm.y; v.z += dm.z; v.w += dm.w;
    } else if (t < NS_S + NS) {
        v = *(const float4*)(ns + ((size_t)b * NS + (t - NS_S)) * D + d0);
    } else {
        v = *(const float4*)(cls + d0);
    }
    *(float4*)(x + (size_t)row * D + d0) = v;
    float s  = v.x + v.y + v.z + v.w;
    float ss = v.x * v.x + v.y * v.y + v.z * v.z + v.w * v.w;
#pragma unroll
    for (int o = 32; o; o >>= 1) { s += __shfl_xor(s, o); ss += __shfl_xor(ss, o); }
    const float mean = s * (1.f / D);
    const float var  = ss * (1.f / D) - mean * mean;
    const float r = rsqrtf(var + EPS);
    float4 wv = *(const float4*)(lnw + d0);
    float4 bv = *(const float4*)(lnb + d0);
    ushort4v o4;
    o4[0] = f2bf((v.x - mean) * r * wv.x + bv.x);
    o4[1] = f2bf((v.y - mean) * r * wv.y + bv.y);
    o4[2] = f2bf((v.z - mean) * r * wv.z + bv.z);
    o4[3] = f2bf((v.w - mean) * r * wv.w + bv.w);
    *(ushort4v*)(xn + (size_t)row * D + d0) = o4;
}

// ---------------- bf16 MFMA GEMM 128x128 dbuf on compact rows (QKV); CLSW remaps ----------------
template<bool OBF, bool CLSW>
__global__ __launch_bounds__(256) void k_gemm_mfma(
    const ushort* __restrict__ A, const ushort* __restrict__ Wt,
    const float* __restrict__ bias, void* __restrict__ Cout,
    const int* __restrict__ len0, const int* __restrict__ len1,
    int N, int K, int nOff)
{
    __shared__ ushort As[2][128 * 64];
    __shared__ ushort Bs[2][128 * 64];
    const int tid = threadIdx.x;
    const int lane = tid & 63, w = tid >> 6;
    const int lo = lane & 15, g = lane >> 4;
    const int wr = w >> 1, wc = w & 1;
    int m0;
    if (CLSW) {
        const int bb = blockIdx.x;
        const int clsrow = offs_of(len0, len1, bb) + len0[bb] + len1[bb] + 32;
        m0 = (clsrow >> 7) << 7;
    } else {
        m0 = blockIdx.x * 128;
        if (m0 >= offs_of(len0, len1, 16)) return;
    }
    const int n0 = (blockIdx.y + nOff) * 128;

    f32x4 zero = {0.f, 0.f, 0.f, 0.f};
    f32x4 acc[4][4];
#pragma unroll
    for (int mi = 0; mi < 4; ++mi)
#pragma unroll
        for (int ni = 0; ni < 4; ++ni) acc[mi][ni] = zero;

    const ushort* srcA[4];
    const ushort* srcB[4];
    int ldsOff[4];
#pragma unroll
    for (int i = 0; i < 4; ++i) {
        const int idx16 = (w * 4 + i) * 64 + lane;
        const int row = idx16 >> 3;
        const int scb = ((idx16 & 7) * 16) ^ ((row & 7) << 4);
        srcA[i] = A  + (size_t)(m0 + row) * K + (scb >> 1);
        srcB[i] = Wt + (size_t)(n0 + row) * K + (scb >> 1);
        ldsOff[i] = (w * 4 + i) * 512;
    }

    const int NT = K >> 6;
#pragma unroll
    for (int i = 0; i < 4; ++i) {
        gload_lds16(srcA[i], &As[0][ldsOff[i]]);
        gload_lds16(srcB[i], &Bs[0][ldsOff[i]]);
    }
    asm volatile("s_waitcnt vmcnt(0)");
    __syncthreads();

    for (int t = 0; t < NT; ++t) {
        const int buf = t & 1;
        if (t + 1 < NT) {
            const int nb = buf ^ 1, ko = (t + 1) * 64;
#pragma unroll
            for (int i = 0; i < 4; ++i) {
                gload_lds16(srcA[i] + ko, &As[nb][ldsOff[i]]);
                gload_lds16(srcB[i] + ko, &Bs[nb][ldsOff[i]]);
            }
        }
#pragma unroll
        for (int kk = 0; kk < 2; ++kk) {
            const int kb = (kk * 64 + g * 16) ^ ((lo & 7) << 4);
            short8 af[4], bfr[4];
#pragma unroll
            for (int mi = 0; mi < 4; ++mi)
                af[mi] = *(const short8*)&As[buf][(wr * 64 + mi * 16 + lo) * 64 + (kb >> 1)];
#pragma unroll
            for (int ni = 0; ni < 4; ++ni)
                bfr[ni] = *(const short8*)&Bs[buf][(wc * 64 + ni * 16 + lo) * 64 + (kb >> 1)];
#pragma unroll
            for (int mi = 0; mi < 4; ++mi)
#pragma unroll
                for (int ni = 0; ni < 4; ++ni)
                    acc[mi][ni] = __builtin_amdgcn_mfma_f32_16x16x32_bf16(
                        af[mi], bfr[ni], acc[mi][ni], 0, 0, 0);
        }
        asm volatile("s_waitcnt vmcnt(0)");
        __syncthreads();
    }

    float bv[4];
#pragma unroll
    for (int ni = 0; ni < 4; ++ni) bv[ni] = bias[n0 + wc * 64 + ni * 16 + lo];
#pragma unroll
    for (int mi = 0; mi < 4; ++mi) {
#pragma unroll
        for (int i = 0; i < 4; ++i) {
            const int row = m0 + wr * 64 + mi * 16 + g * 4 + i;
#pragma unroll
            for (int ni = 0; ni < 4; ++ni) {
                const int col = n0 + wc * 64 + ni * 16 + lo;
                float v = acc[mi][ni][i] + bv[ni];
                if (OBF) ((ushort*)Cout)[(size_t)row * N + col] = f2bf(v);
                else     ((float*)Cout)[(size_t)row * N + col] = v;
            }
        }
    }
}

// ---------------- repack compact K,V -> Kb[bh][832][32], Vt[bh][32][832] ----------------
__global__ __launch_bounds__(256) void k_repack(
    const ushort* __restrict__ qkv, ushort* __restrict__ Kb, ushort* __restrict__ Vt,
    const int* __restrict__ len0, const int* __restrict__ len1)
{
    const int bh = blockIdx.x, tt = blockIdx.y;
    const int b = bh >> 3, h = bh & 7;
    const int nv = len0[b] + len1[b] + 33;
    const int t0 = tt * 64;
    if (t0 >= nv) return;
    const int base = offs_of(len0, len1, b);
    const int tid = threadIdx.x;
    const int r = tid >> 2, c = tid & 3;
    __shared__ ushort vtile[64][40];
    const ushort* kp = qkv + (size_t)(base + t0 + r) * 768 + 256 + h * HD + c * 8;
    ushort8 k8 = *(const ushort8*)kp;
    ushort8 v8 = *(const ushort8*)(kp + 256);
    *(ushort8*)(Kb + ((size_t)bh * TPAD + t0 + r) * HD + c * 8) = k8;
    *(ushort8*)&vtile[r][c * 8] = v8;
    __syncthreads();
    const int d = tid >> 3, cc = tid & 7;
    ushort8 o;
#pragma unroll
    for (int j = 0; j < 8; ++j) o[j] = vtile[cc * 8 + j][d];
    *(ushort8*)(Vt + ((size_t)bh * HD + d) * TPAD + t0 + cc * 8) = o;
}

// ---------------- flash attention: 1-wave blocks, interior fast-path (r12, unchanged) ----------------
template<bool CLSONLY>
__global__ __launch_bounds__(64) void k_flash(
    const ushort* __restrict__ qkv, const ushort* __restrict__ Kb,
    const ushort* __restrict__ Vt, const int* __restrict__ len0,
    const int* __restrict__ len1, ushort* __restrict__ out)
{
    const int bh = blockIdx.x;
    const int b = bh >> 3, h = bh & 7;
    const int clen0 = len0[b], cns = clen0 + len1[b];
    const int nv = cns + 33;
    const int tl = (nv - 1) >> 6, tn0 = cns >> 6;
    int qt;
    if (CLSONLY) qt = tl;
    else { qt = 12 - (int)blockIdx.y; if (qt > tl) return; }

    const int base = offs_of(len0, len1, b);
    const int w = blockIdx.z;
    const int lane = threadIdx.x;
    const int lo = lane & 15, g = lane >> 4;
    const int b4 = g & 1, b5 = g >> 1;
    const int q0t = qt * 64;
    const int qmin = q0t + w * 16, qmax = qmin + 15;
    const int q = qmin + lo;

    short8 qf = *(const short8*)(qkv + (size_t)(base + q) * 768 + h * HD + g * 8);

    const ushort* Kbase = Kb + (size_t)bh * TPAD * HD;
    const ushort* Vbase = Vt + (size_t)bh * HD * TPAD;

    f32x4 acc0 = {0.f, 0.f, 0.f, 0.f}, acc1 = {0.f, 0.f, 0.f, 0.f};
    float mrow = -1e30f, srow = 0.f;

    const int kts = (qmin >= clen0 && qmax < cns) ? (clen0 >> 6) : 0;
    const int nc = qt - kts + 1;
    const int estart = (qt + 1 > tn0) ? (qt + 1) : tn0;
    const int extra = (tl >= estart) ? (tl - estart + 1) : 0;
    const int ntiles = nc + extra;
    auto ktile = [&](int it) { return (it < nc) ? (kts + it) : (estart + (it - nc)); };

    auto xpose = [&](const u32 C0[4], const u32 C1[4], short8& pb0, short8& pb1) {
        u32 pb0u[4], pb1u[4];
#pragma unroll
        for (int n = 0; n < 4; ++n) {
            const u32 F0 = (u32)__shfl_xor((int)C0[n], 16);
            const u32 F1 = (u32)__shfl_xor((int)C1[n], 16);
            const u32 G00 = b4 ? F0 : C0[n];
            const u32 G01 = b4 ? C0[n] : F0;
            const u32 G10 = b4 ? F1 : C1[n];
            const u32 G11 = b4 ? C1[n] : F1;
            const u32 H00 = (u32)__shfl_xor((int)G00, 32);
            const u32 H01 = (u32)__shfl_xor((int)G01, 32);
            const u32 H10 = (u32)__shfl_xor((int)G10, 32);
            const u32 H11 = (u32)__shfl_xor((int)G11, 32);
            const bool keep = (b5 == b4);
            const u32 S00 = keep ? G00 : H00;
            const u32 S01 = keep ? G01 : H01;
            const u32 S10 = keep ? G10 : H10;
            const u32 S11 = keep ? G11 : H11;
            const bool take = (b5 == (n & 1));
            if ((n >> 1) == 0) {
                pb0u[0] = take ? S00 : pb0u[0];
                pb0u[1] = take ? S10 : pb0u[1];
                pb0u[2] = take ? S01 : pb0u[2];
                pb0u[3] = take ? S11 : pb0u[3];
            } else {
                pb1u[0] = take ? S00 : pb1u[0];
                pb1u[1] = take ? S10 : pb1u[1];
                pb1u[2] = take ? S01 : pb1u[2];
                pb1u[3] = take ? S11 : pb1u[3];
            }
        }
        i32x4 t0 = { (int)pb0u[0], (int)pb0u[1], (int)pb0u[2], (int)pb0u[3] };
        i32x4 t1 = { (int)pb1u[0], (int)pb1u[1], (int)pb1u[2], (int)pb1u[3] };
        pb0 = __builtin_bit_cast(short8, t0);
        pb1 = __builtin_bit_cast(short8, t1);
    };

    short8 kf[4];
    {
        const int k0 = ktile(0) * 64;
#pragma unroll
        for (int n = 0; n < 4; ++n)
            kf[n] = *(const short8*)(Kbase + (size_t)(k0 + n * 16 + lo) * HD + g * 8);
    }

    for (int it = 0; it < ntiles; ++it) {
        const int k0 = ktile(it) * 64;

        const bool interior =
            (qmax < clen0 && k0 + 63 <= qmin) ||
            (qmin >= clen0 && qmax < cns && k0 >= clen0 && k0 + 63 <= qmin) ||
            (qmin >= cns && k0 + 63 < cns + 32);

        const ushort* V0 = Vbase + k0;
        short8 a00 = *(const short8*)(V0 + (size_t)lo * TPAD + g * 8);
        short8 a01 = *(const short8*)(V0 + (size_t)lo * TPAD + 32 + g * 8);
        short8 a10 = *(const short8*)(V0 + (size_t)(16 + lo) * TPAD + g * 8);
        short8 a11 = *(const short8*)(V0 + (size_t)(16 + lo) * TPAD + 32 + g * 8);

        float pv[4][4];
        float tmax = -1e30f;
#pragma unroll
        for (int n = 0; n < 4; ++n) {
            f32x4 z = {0.f, 0.f, 0.f, 0.f};
            f32x4 sn = __builtin_amdgcn_mfma_f32_16x16x32_bf16(kf[n], qf, z, 0, 0, 0);
            if (interior) {
#pragma unroll
                for (int i = 0; i < 4; ++i) {
                    pv[n][i] = sn[i] * SCL2;
                    tmax = fmaxf(tmax, pv[n][i]);
                }
            } else {
#pragma unroll
                for (int i = 0; i < 4; ++i) {
                    const int k = k0 + n * 16 + g * 4 + i;
                    const bool win = (k >= cns) & (k < cns + 32);
                    bool m;
                    if (q < clen0)         m = (k <= q) | win;
                    else if (q < cns)      m = ((k >= clen0) & (k <= q)) | win;
                    else if (q < cns + 32) m = (k < cns + 32);
                    else                   m = (k < cns + 32) | (k == q);
                    const float sv = m ? sn[i] * SCL2 : -1e30f;
                    pv[n][i] = sv;
                    tmax = fmaxf(tmax, sv);
                }
            }
        }

        short8 kf2[4];
        if (it + 1 < ntiles) {
            const int k1 = ktile(it + 1) * 64;
#pragma unroll
            for (int n = 0; n < 4; ++n)
                kf2[n] = *(const short8*)(Kbase + (size_t)(k1 + n * 16 + lo) * HD + g * 8);
        }

        tmax = fmaxf(tmax, __shfl_xor(tmax, 16));
        tmax = fmaxf(tmax, __shfl_xor(tmax, 32));
        const float mnew = fmaxf(mrow, tmax);
        if (mnew > mrow) {
            const float scl = exp2f(mrow - mnew);
            srow *= scl;
#pragma unroll
            for (int i = 0; i < 4; ++i) { acc0[i] *= scl; acc1[i] *= scl; }
            mrow = mnew;
        }

        u32 C0[4], C1[4];
        float psum = 0.f;
#pragma unroll
        for (int n = 0; n < 4; ++n) {
            float e0 = (pv[n][0] > -1e29f) ? exp2f(pv[n][0] - mrow) : 0.f;
            float e1 = (pv[n][1] > -1e29f) ? exp2f(pv[n][1] - mrow) : 0.f;
            float e2 = (pv[n][2] > -1e29f) ? exp2f(pv[n][2] - mrow) : 0.f;
            float e3 = (pv[n][3] > -1e29f) ? exp2f(pv[n][3] - mrow) : 0.f;
            psum += (e0 + e1) + (e2 + e3);
            C0[n] = cvtpk(e0, e1);
            C1[n] = cvtpk(e2, e3);
        }
        psum += __shfl_xor(psum, 16);
        psum += __shfl_xor(psum, 32);
        srow += psum;

        short8 pb0, pb1;
        xpose(C0, C1, pb0, pb1);
        acc0 = __builtin_amdgcn_mfma_f32_16x16x32_bf16(a00, pb0, acc0, 0, 0, 0);
        acc0 = __builtin_amdgcn_mfma_f32_16x16x32_bf16(a01, pb1, acc0, 0, 0, 0);
        acc1 = __builtin_amdgcn_mfma_f32_16x16x32_bf16(a10, pb0, acc1, 0, 0, 0);
        acc1 = __builtin_amdgcn_mfma_f32_16x16x32_bf16(a11, pb1, acc1, 0, 0, 0);

#pragma unroll
        for (int n = 0; n < 4; ++n) kf[n] = kf2[n];
    }

    if (q < nv) {
        const float inv = 1.f / fmaxf(srow, 1e-30f);
        ushort* orow = out + (size_t)(base + q) * D + h * HD;
        *(u32*)(orow + g * 4)          = cvtpk(acc0[0] * inv, acc0[1] * inv);
        *(u32*)(orow + g * 4 + 2)      = cvtpk(acc0[2] * inv, acc0[3] * inv);
        *(u32*)(orow + 16 + g * 4)     = cvtpk(acc1[0] * inv, acc1[1] * inv);
        *(u32*)(orow + 16 + g * 4 + 2) = cvtpk(acc1[2] * inv, acc1[3] * inv);
    }
}

// ---------------- second half of layer: OUT+res+LN2 -> FFN1+GELU -> FFN2+res+LN, one kernel ----------------
// MODE 0: writes x (f32) + xn (bf16, LN-next). MODE 1: final LN -> d_out CLS row.
// Direct-global MFMA fragments for all weights (L2-hot); hidden never leaves LDS.
template<int MODE, bool CLSW>
__global__ __launch_bounds__(256) void k_layer2h(
    const ushort* __restrict__ ao, const ushort* __restrict__ Wot,
    const float* __restrict__ bo, const ushort* __restrict__ W1t,
    const float* __restrict__ b1, const ushort* __restrict__ W2t,
    const float* __restrict__ b2, const float* __restrict__ ln2w,
    const float* __restrict__ ln2b, const float* __restrict__ lnnw,
    const float* __restrict__ lnnb, float* __restrict__ x,
    ushort* __restrict__ xn, float* __restrict__ dout,
    const int* __restrict__ len0, const int* __restrict__ len1)
{
    __shared__ ushort xs[64 * 256];   // LN2 output (A for FFN1), XOR-swizzled
    __shared__ ushort hs[64 * 256];   // hidden chunk (A for FFN2); front 2KB aliased as redS/redQ
    float* redS = (float*)hs;         // [64][4] — used only before hs data / after last hs read
    float* redQ = redS + 256;
    const int tid = threadIdx.x, lane = tid & 63, w = tid >> 6;
    const int lo = lane & 15, g = lane >> 4;
    int m0, clsrow = -1, bb = 0;
    if (CLSW) {
        bb = blockIdx.x;
        clsrow = offs_of(len0, len1, bb) + len0[bb] + len1[bb] + 32;
        m0 = (clsrow >> 6) << 6;
    } else {
        m0 = blockIdx.x * 64;
        if (m0 >= offs_of(len0, len1, 16)) return;
    }

    f32x4 zero = {0.f, 0.f, 0.f, 0.f};

    // ---- Phase A: Y = ao @ Wo^T + bo + x ; LN2 -> xs ; x = Y
    f32x4 acc[4][4];
#pragma unroll
    for (int mi = 0; mi < 4; ++mi)
#pragma unroll
        for (int ni = 0; ni < 4; ++ni) acc[mi][ni] = zero;
#pragma unroll
    for (int kk = 0; kk < 8; ++kk) {
        const int kb = kk * 32 + g * 8;
        short8 af[4], bf[4];
#pragma unroll
        for (int mi = 0; mi < 4; ++mi)
            af[mi] = *(const short8*)(ao + (size_t)(m0 + mi * 16 + lo) * 256 + kb);
#pragma unroll
        for (int ni = 0; ni < 4; ++ni)
            bf[ni] = *(const short8*)(Wot + (size_t)(w * 64 + ni * 16 + lo) * 256 + kb);
#pragma unroll
        for (int mi = 0; mi < 4; ++mi)
#pragma unroll
            for (int ni = 0; ni < 4; ++ni)
                acc[mi][ni] = __builtin_amdgcn_mfma_f32_16x16x32_bf16(
                    af[mi], bf[ni], acc[mi][ni], 0, 0, 0);
    }
    float bv[4], l2w_[4], l2b_[4];
#pragma unroll
    for (int ni = 0; ni < 4; ++ni) {
        const int c = w * 64 + ni * 16 + lo;
        bv[ni] = bo[c]; l2w_[ni] = ln2w[c]; l2b_[ni] = ln2b[c];
    }
#pragma unroll
    for (int mi = 0; mi < 4; ++mi) {
#pragma unroll
        for (int i = 0; i < 4; ++i) {
            const int r64 = mi * 16 + g * 4 + i;
            const int row = m0 + r64;
            float s = 0.f, q = 0.f;
#pragma unroll
            for (int ni = 0; ni < 4; ++ni) {
                const int col = w * 64 + ni * 16 + lo;
                float v = acc[mi][ni][i] + bv[ni] + x[(size_t)row * 256 + col];
                acc[mi][ni][i] = v;
                s += v; q += v * v;
            }
            s += __shfl_xor(s, 1); q += __shfl_xor(q, 1);
            s += __shfl_xor(s, 2); q += __shfl_xor(q, 2);
            s += __shfl_xor(s, 4); q += __shfl_xor(q, 4);
            s += __shfl_xor(s, 8); q += __shfl_xor(q, 8);
            if (lo == 0) { redS[r64 * 4 + w] = s; redQ[r64 * 4 + w] = q; }
        }
    }
    __syncthreads();
#pragma unroll
    for (int mi = 0; mi < 4; ++mi) {
#pragma unroll
        for (int i = 0; i < 4; ++i) {
            const int r64 = mi * 16 + g * 4 + i;
            const int row = m0 + r64;
            const float S = redS[r64 * 4 + 0] + redS[r64 * 4 + 1] + redS[r64 * 4 + 2] + redS[r64 * 4 + 3];
            const float Q = redQ[r64 * 4 + 0] + redQ[r64 * 4 + 1] + redQ[r64 * 4 + 2] + redQ[r64 * 4 + 3];
            const float mean = S * (1.f / 256.f);
            const float var  = Q * (1.f / 256.f) - mean * mean;
            const float rstd = rsqrtf(var + EPS);
#pragma unroll
            for (int ni = 0; ni < 4; ++ni) {
                const int col = w * 64 + ni * 16 + lo;
                const float v = acc[mi][ni][i];
                x[(size_t)row * 256 + col] = v;   // Y (re-read in phase C as residual)
                const u32 a = (u32)(((r64 * 256 + col) * 2) ^ ((r64 & 7) << 4));
                *(ushort*)((char*)xs + a) = f2bf((v - mean) * rstd * l2w_[ni] + l2b_[ni]);
            }
        }
    }
    __syncthreads();   // xs ready; redS region about to be reused as hs data

    // ---- Phase B: FFN through LDS (4 chunks of 256 hidden cols)
    f32x4 o2[4][4];
#pragma unroll
    for (int mi = 0; mi < 4; ++mi)
#pragma unroll
        for (int ni = 0; ni < 4; ++ni) o2[mi][ni] = zero;

    for (int c = 0; c < 4; ++c) {
        f32x4 hc[4][4];
#pragma unroll
        for (int mi = 0; mi < 4; ++mi)
#pragma unroll
            for (int ni = 0; ni < 4; ++ni) hc[mi][ni] = zero;
#pragma unroll
        for (int kk = 0; kk < 8; ++kk) {
            const int kb = kk * 32 + g * 8;
            short8 af[4], bf[4];
#pragma unroll
            for (int mi = 0; mi < 4; ++mi) {
                const int r = mi * 16 + lo;
                const u32 a = (u32)(((r * 256 + kb) * 2) ^ ((lo & 7) << 4));
                af[mi] = *(const short8*)((const char*)xs + a);
            }
#pragma unroll
            for (int ni = 0; ni < 4; ++ni)
                bf[ni] = *(const short8*)(W1t + (size_t)(c * 256 + w * 64 + ni * 16 + lo) * 256 + kb);
#pragma unroll
            for (int mi = 0; mi < 4; ++mi)
#pragma unroll
                for (int ni = 0; ni < 4; ++ni)
                    hc[mi][ni] = __builtin_amdgcn_mfma_f32_16x16x32_bf16(
                        af[mi], bf[ni], hc[mi][ni], 0, 0, 0);
        }
        float b1v[4];
#pragma unroll
        for (int ni = 0; ni < 4; ++ni) b1v[ni] = b1[c * 256 + w * 64 + ni * 16 + lo];
#pragma unroll
        for (int mi = 0; mi < 4; ++mi) {
#pragma unroll
            for (int i = 0; i < 4; ++i) {
                const int r64 = mi * 16 + g * 4 + i;
#pragma unroll
                for (int ni = 0; ni < 4; ++ni) {
                    const int col = w * 64 + ni * 16 + lo;
                    float v = hc[mi][ni][i] + b1v[ni];
                    v = 0.5f * v * (1.0f + erff(v * 0.70710678118654752f));
                    const u32 a = (u32)(((r64 * 256 + col) * 2) ^ ((r64 & 7) << 4));
                    *(ushort*)((char*)hs + a) = f2bf(v);
                }
            }
        }
        __syncthreads();   // hs chunk ready
#pragma unroll
        for (int kk = 0; kk < 8; ++kk) {
            const int kb = kk * 32 + g * 8;
            short8 af[4], bf[4];
#pragma unroll
            for (int mi = 0; mi < 4; ++mi) {
                const int r = mi * 16 + lo;
                const u32 a = (u32)(((r * 256 + kb) * 2) ^ ((lo & 7) << 4));
                af[mi] = *(const short8*)((const char*)hs + a);
            }
#pragma unroll
            for (int ni = 0; ni < 4; ++ni)
                bf[ni] = *(const short8*)(W2t + (size_t)(w * 64 + ni * 16 + lo) * 1024 + c * 256 + kb);
#pragma unroll
            for (int mi = 0; mi < 4; ++mi)
#pragma unroll
                for (int ni = 0; ni < 4; ++ni)
                    o2[mi][ni] = __builtin_amdgcn_mfma_f32_16x16x32_bf16(
                        af[mi], bf[ni], o2[mi][ni], 0, 0, 0);
        }
        __syncthreads();   // all reads of hs done before next chunk overwrites
    }

    // ---- Phase C: v = o2 + b2 + Y ; LN-next -> outputs
    float b2v[4], lnw_[4], lnb_[4];
#pragma unroll
    for (int ni = 0; ni < 4; ++ni) {
        const int c = w * 64 + ni * 16 + lo;
        b2v[ni] = b2[c]; lnw_[ni] = lnnw[c]; lnb_[ni] = lnnb[c];
    }
#pragma unroll
    for (int mi = 0; mi < 4; ++mi) {
#pragma unroll
        for (int i = 0; i < 4; ++i) {
            const int r64 = mi * 16 + g * 4 + i;
            const int row = m0 + r64;
            float s = 0.f, q = 0.f;
#pragma unroll
            for (int ni = 0; ni < 4; ++ni) {
                const int col = w * 64 + ni * 16 + lo;
                float v = o2[mi][ni][i] + b2v[ni] + x[(size_t)row * 256 + col];
                o2[mi][ni][i] = v;
                s += v; q += v * v;
            }
            s += __shfl_xor(s, 1); q += __shfl_xor(q, 1);
            s += __shfl_xor(s, 2); q += __shfl_xor(q, 2);
            s += __shfl_xor(s, 4); q += __shfl_xor(q, 4);
            s += __shfl_xor(s, 8); q += __shfl_xor(q, 8);
            if (lo == 0) { redS[r64 * 4 + w] = s; redQ[r64 * 4 + w] = q; }
        }
    }
    __syncthreads();
#pragma unroll
    for (int mi = 0; mi < 4; ++mi) {
#pragma unroll
        for (int i = 0; i < 4; ++i) {
            const int r64 = mi * 16 + g * 4 + i;
            const int row = m0 + r64;
            const float S = redS[r64 * 4 + 0] + redS[r64 * 4 + 1] + redS[r64 * 4 + 2] + redS[r64 * 4 + 3];
            const float Q = redQ[r64 * 4 + 0] + redQ[r64 * 4 + 1] + redQ[r64 * 4 + 2] + redQ[r64 * 4 + 3];
            const float mean = S * (1.f / 256.f);
            const float var  = Q * (1.f / 256.f) - mean * mean;
            const float rstd = rsqrtf(var + EPS);
            if (MODE == 0) {
#pragma unroll
                for (int ni = 0; ni < 4; ++ni) {
                    const int col = w * 64 + ni * 16 + lo;
                    const float v = o2[mi][ni][i];
                    x[(size_t)row * 256 + col] = v;
                    xn[(size_t)row * 256 + col] = f2bf((v - mean) * rstd * lnw_[ni] + lnb_[ni]);
                }
            } else {
                if (row == clsrow) {
#pragma unroll
                    for (int ni = 0; ni < 4; ++ni) {
                        const int col = w * 64 + ni * 16 + lo;
                        dout[(size_t)bb * 256 + col] =
                            (o2[mi][ni][i] - mean) * rstd * lnw_[ni] + lnb_[ni];
                    }
                }
            }
        }
    }
}

extern "C" void kernel_launch(void* const* d_in, const int* in_sizes, int n_in,
                              void* d_out, int out_size, void* d_ws, size_t ws_size,
                              hipStream_t stream)
{
    const float* seq0 = (const float*)d_in[0];
    const float* seq1 = (const float*)d_in[1];
    const int*   len0 = (const int*)d_in[2];
    const int*   len1 = (const int*)d_in[3];
    const float* nst  = (const float*)d_in[4];
    const float* dom  = (const float*)d_in[5];
    const float* cls  = (const float*)d_in[6];
    const float* ln1w = (const float*)d_in[7];
    const float* ln1b = (const float*)d_in[8];
    const float* qkvw = (const float*)d_in[9];
    const float* qkvb = (const float*)d_in[10];
    const float* outw = (const float*)d_in[11];
    const float* outb = (const float*)d_in[12];
    const float* ln2w = (const float*)d_in[13];
    const float* ln2b = (const float*)d_in[14];
    const float* f1w  = (const float*)d_in[15];
    const float* f1b  = (const float*)d_in[16];
    const float* f2w  = (const float*)d_in[17];
    const float* f2b  = (const float*)d_in[18];
    const float* flnw = (const float*)d_in[19];
    const float* flnb = (const float*)d_in[20];

    float*  x   = (float*)d_ws;                         // ROWP*256 f32
    ushort* xn  = (ushort*)(x + (size_t)ROWP * D);      // ROWP*256 bf16
    ushort* big = xn + (size_t)ROWP * D;                // ROWP*1024 bf16 (qkv rows)
    ushort* Kb  = big + (size_t)ROWP * HM * D;          // 128*832*32
    ushort* Vt  = Kb + (size_t)B * H * TPAD * HD;       // 128*32*832
    ushort* qkvw_t = Vt + (size_t)B * H * TPAD * HD;    // NL*768*256
    ushort* outw_t = qkvw_t + (size_t)NL * 768 * 256;   // NL*256*256
    ushort* f1w_t  = outw_t + (size_t)NL * 256 * 256;   // NL*1024*256
    ushort* f2w_t  = f1w_t  + (size_t)NL * 1024 * 256;  // NL*256*1024

    k_wprep_all<<<3072, 256, 0, stream>>>(qkvw, outw, f1w, f2w,
                                          qkvw_t, outw_t, f1w_t, f2w_t);
    k_build_ln<<<ROWP / 4, 256, 0, stream>>>(seq0, seq1, nst, dom, cls,
                                             ln1w, ln1b, len0, len1, x, xn);

    const int gmm = ROWP / 128;   // 104
    const int gf  = ROWP / 64;    // 208

    for (int l = 0; l < NL; ++l) {
        const bool last = (l == NL - 1);
        // QKV
        if (!last) {
            k_gemm_mfma<true, false><<<dim3(gmm, 6), 256, 0, stream>>>(
                xn, qkvw_t + (size_t)l * 768 * 256, qkvb + (size_t)l * 3 * D, big,
                len0, len1, 3 * D, D, 0);
        } else {
            k_gemm_mfma<true, false><<<dim3(gmm, 4), 256, 0, stream>>>(
                xn, qkvw_t + (size_t)l * 768 * 256, qkvb + (size_t)l * 3 * D, big,
                len0, len1, 3 * D, D, 2);
            k_gemm_mfma<true, true><<<dim3(B, 2), 256, 0, stream>>>(
                xn, qkvw_t + (size_t)l * 768 * 256, qkvb + (size_t)l * 3 * D, big,
                len0, len1, 3 * D, D, 0);
        }
        k_repack<<<dim3(B * H, 13), 256, 0, stream>>>(big, Kb, Vt, len0, len1);
        if (!last)
            k_flash<false><<<dim3(B * H, 13, 4), 64, 0, stream>>>(
                big, Kb, Vt, len0, len1, xn);
        else
            k_flash<true><<<dim3(B * H, 1, 4), 64, 0, stream>>>(
                big, Kb, Vt, len0, len1, xn);
        // second half of layer, fused
        if (!last)
            k_layer2h<0, false><<<gf, 256, 0, stream>>>(
                xn, outw_t + (size_t)l * 256 * 256, outb + (size_t)l * D,
                f1w_t + (size_t)l * 1024 * 256, f1b + (size_t)l * HM * D,
                f2w_t + (size_t)l * 256 * 1024, f2b + (size_t)l * D,
                ln2w + l * D, ln2b + l * D,
                ln1w + (l + 1) * D, ln1b + (l + 1) * D,
                x, xn, nullptr, len0, len1);
        else
            k_layer2h<1, true><<<B, 256, 0, stream>>>(
                xn, outw_t + (size_t)l * 256 * 256, outb + (size_t)l * D,
                f1w_t + (size_t)l * 1024 * 256, f1b + (size_t)l * HM * D,
                f2w_t + (size_t)l * 256 * 1024, f2b + (size_t)l * D,
                ln2w + l * D, ln2b + l * D, flnw, flnb,
                x, xn, (float*)d_out, len0, len1);
    }
}

// Round 14
// 466.646 us; speedup vs baseline: 1.1214x; 1.1214x over previous
//
#include <hip/hip_runtime.h>
#include <hip/hip_bf16.h>
#include <math.h>

typedef __attribute__((ext_vector_type(8))) unsigned short ushort8;
typedef __attribute__((ext_vector_type(8))) short short8;
typedef __attribute__((ext_vector_type(4))) float f32x4;
typedef __attribute__((ext_vector_type(4))) unsigned short ushort4v;
typedef __attribute__((ext_vector_type(4))) int i32x4;
typedef unsigned int u32;

namespace {
constexpr int B = 16, L0 = 512, L1 = 256, NS = 32, D = 256, H = 8, NL = 4, HM = 4;
constexpr int T = L0 + L1 + NS + 1;   // 801
constexpr int HD = D / H;             // 32
constexpr int NS_S = L0 + L1;         // 768
constexpr int TPAD = 832;             // 13*64 (per-bh V stride)
constexpr int ROWP = 13312;           // 16*832 compact-row capacity
constexpr float EPS = 1e-5f;
constexpr float SCL2  = 0.17677669529663687f * 1.4426950408889634f;  // SCALE*log2e
}

__device__ __forceinline__ ushort f2bf(float f) {
    union { float f; unsigned u; } v; v.f = f;
    return (ushort)((v.u + 0x7fffu + ((v.u >> 16) & 1u)) >> 16);
}

__device__ __forceinline__ u32 cvtpk(float a, float b) {
    u32 r;
    asm("v_cvt_pk_bf16_f32 %0, %1, %2" : "=v"(r) : "v"(a), "v"(b));
    return r;
}

__device__ __forceinline__ void gload_lds16(const void* g, void* l) {
    __builtin_amdgcn_global_load_lds(
        (const __attribute__((address_space(1))) u32*)g,
        (__attribute__((address_space(3))) u32*)l, 16, 0, 0);
}

// compact-row prefix: offset of batch b (64-aligned caps); b=16 -> total rows
__device__ __forceinline__ int offs_of(const int* __restrict__ l0,
                                       const int* __restrict__ l1, int b) {
    int acc = 0;
    for (int j = 0; j < b; ++j) acc += ((l0[j] + l1[j] + 96) >> 6) << 6;
    return acc;
}

// ---------------- unified weight prep: all four W[K][N] f32 -> W^T[N][K] bf16 ----------------
__global__ __launch_bounds__(256) void k_wprep_all(
    const float* __restrict__ qkvw, const float* __restrict__ outw,
    const float* __restrict__ f1w, const float* __restrict__ f2w,
    ushort* __restrict__ qkvt, ushort* __restrict__ outt,
    ushort* __restrict__ f1t, ushort* __restrict__ f2t)
{
    int id = blockIdx.x;
    const float* src; ushort* dst; int K, N;
    if (id < 768)        { src = qkvw; dst = qkvt; K = 256;  N = 768;  }
    else if (id < 1024)  { id -= 768;  src = outw; dst = outt; K = 256; N = 256; }
    else if (id < 2048)  { id -= 1024; src = f1w;  dst = f1t;  K = 256; N = 1024; }
    else                 { id -= 2048; src = f2w;  dst = f2t;  K = 1024; N = 256; }
    const int ktiles = K >> 5, per = ktiles * (N >> 5);
    const int layer = id / per, rem = id % per;
    const int kb = (rem % ktiles) * 32, nb = (rem / ktiles) * 32;
    src += (size_t)layer * K * N; dst += (size_t)layer * K * N;

    __shared__ float t[32][33];
    const int c = threadIdx.x & 31, r8 = threadIdx.x >> 5;
#pragma unroll
    for (int rr = 0; rr < 32; rr += 8)
        t[r8 + rr][c] = src[(size_t)(kb + r8 + rr) * N + nb + c];
    __syncthreads();
#pragma unroll
    for (int rr = 0; rr < 32; rr += 8)
        dst[(size_t)(nb + r8 + rr) * K + kb + c] = f2bf(t[c][r8 + rr]);
}

// ---------------- build compact x + first LN1 fused; padding rows zeroed ----------------
__global__ __launch_bounds__(256) void k_build_ln(
    const float* __restrict__ s0, const float* __restrict__ s1,
    const float* __restrict__ ns, const float* __restrict__ dom,
    const float* __restrict__ cls, const float* __restrict__ lnw,
    const float* __restrict__ lnb, const int* __restrict__ len0,
    const int* __restrict__ len1, float* __restrict__ x, ushort* __restrict__ xn)
{
    const int wid = threadIdx.x >> 6, lane = threadIdx.x & 63;
    const int row = blockIdx.x * 4 + wid;
    if (row >= ROWP) return;
    const int d0 = lane * 4;

    int bsel = -1, t = -1, acc = 0;
    for (int j = 0; j < 16; ++j) {
        const int n0 = len0[j], n1 = len1[j];
        const int nvj = n0 + n1 + 33;
        const int cap = ((nvj + 63) >> 6) << 6;
        if (row < acc + cap) {
            const int loc = row - acc;
            if (loc < nvj)
                t = (loc < n0) ? loc
                  : (loc < n0 + n1) ? (L0 + loc - n0)
                  : (NS_S + loc - n0 - n1);
            bsel = j;
            break;
        }
        acc += cap;
    }
    if (bsel < 0 || t < 0) {
        float4 z = {0.f, 0.f, 0.f, 0.f};
        *(float4*)(x + (size_t)row * D + d0) = z;
        ushort4v z4 = {0, 0, 0, 0};
        *(ushort4v*)(xn + (size_t)row * D + d0) = z4;
        return;
    }
    const int b = bsel;
    float4 v;
    if (t < L0) {
        v = *(const float4*)(s0 + ((size_t)b * L0 + t) * D + d0);
        float4 dm = *(const float4*)(dom + d0);
        v.x += dm.x; v.y += dm.y; v.z += dm.z; v.w += dm.w;
    } else if (t < NS_S) {
        v = *(const float4*)(s1 + ((size_t)b * L1 + (t - L0)) * D + d0);
        float4 dm = *(const float4*)(dom + D + d0);
        v.x += dm.x; v.y += dm.y; v.z += dm.z; v.w += dm.w;
    } else if (t < NS_S + NS) {
        v = *(const float4*)(ns + ((size_t)b * NS + (t - NS_S)) * D + d0);
    } else {
        v = *(const float4*)(cls + d0);
    }
    *(float4*)(x + (size_t)row * D + d0) = v;
    float s  = v.x + v.y + v.z + v.w;
    float ss = v.x * v.x + v.y * v.y + v.z * v.z + v.w * v.w;
#pragma unroll
    for (int o = 32; o; o >>= 1) { s += __shfl_xor(s, o); ss += __shfl_xor(ss, o); }
    const float mean = s * (1.f / D);
    const float var  = ss * (1.f / D) - mean * mean;
    const float r = rsqrtf(var + EPS);
    float4 wv = *(const float4*)(lnw + d0);
    float4 bv = *(const float4*)(lnb + d0);
    ushort4v o4;
    o4[0] = f2bf((v.x - mean) * r * wv.x + bv.x);
    o4[1] = f2bf((v.y - mean) * r * wv.y + bv.y);
    o4[2] = f2bf((v.z - mean) * r * wv.z + bv.z);
    o4[3] = f2bf((v.w - mean) * r * wv.w + bv.w);
    *(ushort4v*)(xn + (size_t)row * D + d0) = o4;
}

// ---------------- bf16 MFMA GEMM 128x128 dbuf on compact rows; CLSW remaps to cls window ----------------
template<bool GELU, bool OBF, bool CLSW>
__global__ __launch_bounds__(256) void k_gemm_mfma(
    const ushort* __restrict__ A, const ushort* __restrict__ Wt,
    const float* __restrict__ bias, void* __restrict__ Cout,
    const int* __restrict__ len0, const int* __restrict__ len1,
    int N, int K, int nOff)
{
    __shared__ ushort As[2][128 * 64];
    __shared__ ushort Bs[2][128 * 64];
    const int tid = threadIdx.x;
    const int lane = tid & 63, w = tid >> 6;
    const int lo = lane & 15, g = lane >> 4;
    const int wr = w >> 1, wc = w & 1;
    int m0;
    if (CLSW) {
        const int bb = blockIdx.x;
        const int clsrow = offs_of(len0, len1, bb) + len0[bb] + len1[bb] + 32;
        m0 = (clsrow >> 7) << 7;
    } else {
        m0 = blockIdx.x * 128;
        if (m0 >= offs_of(len0, len1, 16)) return;
    }
    const int n0 = (blockIdx.y + nOff) * 128;

    f32x4 zero = {0.f, 0.f, 0.f, 0.f};
    f32x4 acc[4][4];
#pragma unroll
    for (int mi = 0; mi < 4; ++mi)
#pragma unroll
        for (int ni = 0; ni < 4; ++ni) acc[mi][ni] = zero;

    const ushort* srcA[4];
    const ushort* srcB[4];
    int ldsOff[4];
#pragma unroll
    for (int i = 0; i < 4; ++i) {
        const int idx16 = (w * 4 + i) * 64 + lane;
        const int row = idx16 >> 3;
        const int scb = ((idx16 & 7) * 16) ^ ((row & 7) << 4);
        srcA[i] = A  + (size_t)(m0 + row) * K + (scb >> 1);
        srcB[i] = Wt + (size_t)(n0 + row) * K + (scb >> 1);
        ldsOff[i] = (w * 4 + i) * 512;
    }

    const int NT = K >> 6;
#pragma unroll
    for (int i = 0; i < 4; ++i) {
        gload_lds16(srcA[i], &As[0][ldsOff[i]]);
        gload_lds16(srcB[i], &Bs[0][ldsOff[i]]);
    }
    asm volatile("s_waitcnt vmcnt(0)");
    __syncthreads();

    for (int t = 0; t < NT; ++t) {
        const int buf = t & 1;
        if (t + 1 < NT) {
            const int nb = buf ^ 1, ko = (t + 1) * 64;
#pragma unroll
            for (int i = 0; i < 4; ++i) {
                gload_lds16(srcA[i] + ko, &As[nb][ldsOff[i]]);
                gload_lds16(srcB[i] + ko, &Bs[nb][ldsOff[i]]);
            }
        }
#pragma unroll
        for (int kk = 0; kk < 2; ++kk) {
            const int kb = (kk * 64 + g * 16) ^ ((lo & 7) << 4);
            short8 af[4], bfr[4];
#pragma unroll
            for (int mi = 0; mi < 4; ++mi)
                af[mi] = *(const short8*)&As[buf][(wr * 64 + mi * 16 + lo) * 64 + (kb >> 1)];
#pragma unroll
            for (int ni = 0; ni < 4; ++ni)
                bfr[ni] = *(const short8*)&Bs[buf][(wc * 64 + ni * 16 + lo) * 64 + (kb >> 1)];
#pragma unroll
            for (int mi = 0; mi < 4; ++mi)
#pragma unroll
                for (int ni = 0; ni < 4; ++ni)
                    acc[mi][ni] = __builtin_amdgcn_mfma_f32_16x16x32_bf16(
                        af[mi], bfr[ni], acc[mi][ni], 0, 0, 0);
        }
        asm volatile("s_waitcnt vmcnt(0)");
        __syncthreads();
    }

    float bv[4];
#pragma unroll
    for (int ni = 0; ni < 4; ++ni) bv[ni] = bias[n0 + wc * 64 + ni * 16 + lo];
#pragma unroll
    for (int mi = 0; mi < 4; ++mi) {
#pragma unroll
        for (int i = 0; i < 4; ++i) {
            const int row = m0 + wr * 64 + mi * 16 + g * 4 + i;
#pragma unroll
            for (int ni = 0; ni < 4; ++ni) {
                const int col = n0 + wc * 64 + ni * 16 + lo;
                float v = acc[mi][ni][i] + bv[ni];
                if (GELU) v = 0.5f * v * (1.0f + erff(v * 0.70710678118654752f));
                if (OBF) ((ushort*)Cout)[(size_t)row * N + col] = f2bf(v);
                else     ((float*)Cout)[(size_t)row * N + col] = v;
            }
        }
    }
}

// ---------------- fused GEMM (BM=64, BN=256) + residual + LayerNorm on compact rows ----------------
template<int MODE, bool CLSW>
__global__ __launch_bounds__(256) void k_gemm_fused(
    const ushort* __restrict__ A, const ushort* __restrict__ Wt,
    const float* __restrict__ bias, const float* __restrict__ res,
    const float* __restrict__ lnw, const float* __restrict__ lnb,
    float* __restrict__ xout, ushort* __restrict__ xnout,
    float* __restrict__ dout, const int* __restrict__ len0,
    const int* __restrict__ len1, int K)
{
    __shared__ ushort As[2][64 * 64];
    __shared__ ushort Bs[2][256 * 64];
    __shared__ float redS[64][4];
    __shared__ float redQ[64][4];
    const int tid = threadIdx.x;
    const int lane = tid & 63, w = tid >> 6;
    const int lo = lane & 15, g = lane >> 4;
    int m0, clsrow = -1, bb = 0;
    if (CLSW) {
        bb = blockIdx.x;
        clsrow = offs_of(len0, len1, bb) + len0[bb] + len1[bb] + 32;
        m0 = (clsrow >> 6) << 6;
    } else {
        m0 = blockIdx.x * 64;
        if (m0 >= offs_of(len0, len1, 16)) return;
    }

    f32x4 zero = {0.f, 0.f, 0.f, 0.f};
    f32x4 acc[4][4];
#pragma unroll
    for (int mi = 0; mi < 4; ++mi)
#pragma unroll
        for (int ni = 0; ni < 4; ++ni) acc[mi][ni] = zero;

    const ushort* srcA[2]; int ldsOffA[2];
    const ushort* srcB[8]; int ldsOffB[8];
#pragma unroll
    for (int j = 0; j < 2; ++j) {
        const int idx16 = j * 256 + tid;
        const int row = idx16 >> 3;
        const int scb = ((idx16 & 7) * 16) ^ ((row & 7) << 4);
        srcA[j] = A + (size_t)(m0 + row) * K + (scb >> 1);
        ldsOffA[j] = idx16 * 8;
    }
#pragma unroll
    for (int j = 0; j < 8; ++j) {
        const int idx16 = j * 256 + tid;
        const int row = idx16 >> 3;
        const int scb = ((idx16 & 7) * 16) ^ ((row & 7) << 4);
        srcB[j] = Wt + (size_t)row * K + (scb >> 1);
        ldsOffB[j] = idx16 * 8;
    }

    const int NT = K >> 6;
#pragma unroll
    for (int j = 0; j < 2; ++j) gload_lds16(srcA[j], &As[0][ldsOffA[j]]);
#pragma unroll
    for (int j = 0; j < 8; ++j) gload_lds16(srcB[j], &Bs[0][ldsOffB[j]]);
    asm volatile("s_waitcnt vmcnt(0)");
    __syncthreads();

    for (int t = 0; t < NT; ++t) {
        const int buf = t & 1;
        if (t + 1 < NT) {
            const int nb = buf ^ 1, ko = (t + 1) * 64;
#pragma unroll
            for (int j = 0; j < 2; ++j) gload_lds16(srcA[j] + ko, &As[nb][ldsOffA[j]]);
#pragma unroll
            for (int j = 0; j < 8; ++j) gload_lds16(srcB[j] + ko, &Bs[nb][ldsOffB[j]]);
        }
#pragma unroll
        for (int kk = 0; kk < 2; ++kk) {
            const int kb = (kk * 64 + g * 16) ^ ((lo & 7) << 4);
            short8 af[4], bfr[4];
#pragma unroll
            for (int mi = 0; mi < 4; ++mi)
                af[mi] = *(const short8*)&As[buf][(mi * 16 + lo) * 64 + (kb >> 1)];
#pragma unroll
            for (int ni = 0; ni < 4; ++ni)
                bfr[ni] = *(const short8*)&Bs[buf][(w * 64 + ni * 16 + lo) * 64 + (kb >> 1)];
#pragma unroll
            for (int mi = 0; mi < 4; ++mi)
#pragma unroll
                for (int ni = 0; ni < 4; ++ni)
                    acc[mi][ni] = __builtin_amdgcn_mfma_f32_16x16x32_bf16(
                        af[mi], bfr[ni], acc[mi][ni], 0, 0, 0);
        }
        asm volatile("s_waitcnt vmcnt(0)");
        __syncthreads();
    }

    float bv[4], lw[4], lb[4];
#pragma unroll
    for (int ni = 0; ni < 4; ++ni) {
        const int c = w * 64 + ni * 16 + lo;
        bv[ni] = bias[c]; lw[ni] = lnw[c]; lb[ni] = lnb[c];
    }
#pragma unroll
    for (int mi = 0; mi < 4; ++mi) {
#pragma unroll
        for (int i = 0; i < 4; ++i) {
            const int r64 = mi * 16 + g * 4 + i;
            const int row = m0 + r64;
            float s = 0.f, q = 0.f;
#pragma unroll
            for (int ni = 0; ni < 4; ++ni) {
                const int col = w * 64 + ni * 16 + lo;
                float v = acc[mi][ni][i] + bv[ni] + res[(size_t)row * 256 + col];
                acc[mi][ni][i] = v;
                s += v; q += v * v;
            }
            s += __shfl_xor(s, 1); q += __shfl_xor(q, 1);
            s += __shfl_xor(s, 2); q += __shfl_xor(q, 2);
            s += __shfl_xor(s, 4); q += __shfl_xor(q, 4);
            s += __shfl_xor(s, 8); q += __shfl_xor(q, 8);
            if (lo == 0) { redS[r64][w] = s; redQ[r64][w] = q; }
        }
    }
    __syncthreads();
#pragma unroll
    for (int mi = 0; mi < 4; ++mi) {
#pragma unroll
        for (int i = 0; i < 4; ++i) {
            const int r64 = mi * 16 + g * 4 + i;
            const int row = m0 + r64;
            const float S = redS[r64][0] + redS[r64][1] + redS[r64][2] + redS[r64][3];
            const float Q = redQ[r64][0] + redQ[r64][1] + redQ[r64][2] + redQ[r64][3];
            const float mean = S * (1.f / 256.f);
            const float var  = Q * (1.f / 256.f) - mean * mean;
            const float rstd = rsqrtf(var + EPS);
            if (MODE == 0) {
#pragma unroll
                for (int ni = 0; ni < 4; ++ni) {
                    const int col = w * 64 + ni * 16 + lo;
                    const float v = acc[mi][ni][i];
                    xout[(size_t)row * 256 + col] = v;
                    xnout[(size_t)row * 256 + col] = f2bf((v - mean) * rstd * lw[ni] + lb[ni]);
                }
            } else {
                if (row == clsrow) {
#pragma unroll
                    for (int ni = 0; ni < 4; ++ni) {
                        const int col = w * 64 + ni * 16 + lo;
                        dout[(size_t)bb * 256 + col] =
                            (acc[mi][ni][i] - mean) * rstd * lw[ni] + lb[ni];
                    }
                }
            }
        }
    }
}

// ---------------- repack V only -> Vt[bh][32][832] (K read directly from qkv in flash) ----------------
__global__ __launch_bounds__(256) void k_repack(
    const ushort* __restrict__ qkv, ushort* __restrict__ Vt,
    const int* __restrict__ len0, const int* __restrict__ len1)
{
    const int bh = blockIdx.x, tt = blockIdx.y;
    const int b = bh >> 3, h = bh & 7;
    const int nv = len0[b] + len1[b] + 33;
    const int t0 = tt * 64;
    if (t0 >= nv) return;
    const int base = offs_of(len0, len1, b);
    const int tid = threadIdx.x;
    const int r = tid >> 2, c = tid & 3;
    __shared__ ushort vtile[64][40];
    const ushort* vp = qkv + (size_t)(base + t0 + r) * 768 + 512 + h * HD + c * 8;
    ushort8 v8 = *(const ushort8*)vp;
    *(ushort8*)&vtile[r][c * 8] = v8;
    __syncthreads();
    const int d = tid >> 3, cc = tid & 7;
    ushort8 o;
#pragma unroll
    for (int j = 0; j < 8; ++j) o[j] = vtile[cc * 8 + j][d];
    *(ushort8*)(Vt + ((size_t)bh * HD + d) * TPAD + t0 + cc * 8) = o;
}

// ---------------- flash attention: 1-wave blocks, K direct from qkv, interior fast-path ----------------
template<bool CLSONLY>
__global__ __launch_bounds__(64) void k_flash(
    const ushort* __restrict__ qkv, const ushort* __restrict__ Vt,
    const int* __restrict__ len0, const int* __restrict__ len1,
    ushort* __restrict__ out)
{
    const int bh = blockIdx.x;
    const int b = bh >> 3, h = bh & 7;
    const int clen0 = len0[b], cns = clen0 + len1[b];
    const int nv = cns + 33;
    const int tl = (nv - 1) >> 6, tn0 = cns >> 6;
    int qt;
    if (CLSONLY) qt = tl;
    else { qt = 12 - (int)blockIdx.y; if (qt > tl) return; }

    const int base = offs_of(len0, len1, b);
    const int w = blockIdx.z;
    const int lane = threadIdx.x;
    const int lo = lane & 15, g = lane >> 4;
    const int b4 = g & 1, b5 = g >> 1;
    const int q0t = qt * 64;
    const int qmin = q0t + w * 16, qmax = qmin + 15;
    const int q = qmin + lo;

    short8 qf = *(const short8*)(qkv + (size_t)(base + q) * 768 + h * HD + g * 8);

    // K rows live in qkv at row stride 768 (cols 256..511 per head slice)
    const ushort* Kbase = qkv + (size_t)base * 768 + 256 + h * HD;
    const ushort* Vbase = Vt + (size_t)bh * HD * TPAD;

    f32x4 acc0 = {0.f, 0.f, 0.f, 0.f}, acc1 = {0.f, 0.f, 0.f, 0.f};
    float mrow = -1e30f, srow = 0.f;

    const int kts = (qmin >= clen0 && qmax < cns) ? (clen0 >> 6) : 0;
    const int nc = qt - kts + 1;
    const int estart = (qt + 1 > tn0) ? (qt + 1) : tn0;
    const int extra = (tl >= estart) ? (tl - estart + 1) : 0;
    const int ntiles = nc + extra;
    auto ktile = [&](int it) { return (it < nc) ? (kts + it) : (estart + (it - nc)); };

    auto xpose = [&](const u32 C0[4], const u32 C1[4], short8& pb0, short8& pb1) {
        u32 pb0u[4], pb1u[4];
#pragma unroll
        for (int n = 0; n < 4; ++n) {
            const u32 F0 = (u32)__shfl_xor((int)C0[n], 16);
            const u32 F1 = (u32)__shfl_xor((int)C1[n], 16);
            const u32 G00 = b4 ? F0 : C0[n];
            const u32 G01 = b4 ? C0[n] : F0;
            const u32 G10 = b4 ? F1 : C1[n];
            const u32 G11 = b4 ? C1[n] : F1;
            const u32 H00 = (u32)__shfl_xor((int)G00, 32);
            const u32 H01 = (u32)__shfl_xor((int)G01, 32);
            const u32 H10 = (u32)__shfl_xor((int)G10, 32);
            const u32 H11 = (u32)__shfl_xor((int)G11, 32);
            const bool keep = (b5 == b4);
            const u32 S00 = keep ? G00 : H00;
            const u32 S01 = keep ? G01 : H01;
            const u32 S10 = keep ? G10 : H10;
            const u32 S11 = keep ? G11 : H11;
            const bool take = (b5 == (n & 1));
            if ((n >> 1) == 0) {
                pb0u[0] = take ? S00 : pb0u[0];
                pb0u[1] = take ? S10 : pb0u[1];
                pb0u[2] = take ? S01 : pb0u[2];
                pb0u[3] = take ? S11 : pb0u[3];
            } else {
                pb1u[0] = take ? S00 : pb1u[0];
                pb1u[1] = take ? S10 : pb1u[1];
                pb1u[2] = take ? S01 : pb1u[2];
                pb1u[3] = take ? S11 : pb1u[3];
            }
        }
        i32x4 t0 = { (int)pb0u[0], (int)pb0u[1], (int)pb0u[2], (int)pb0u[3] };
        i32x4 t1 = { (int)pb1u[0], (int)pb1u[1], (int)pb1u[2], (int)pb1u[3] };
        pb0 = __builtin_bit_cast(short8, t0);
        pb1 = __builtin_bit_cast(short8, t1);
    };

    short8 kf[4];
    {
        const int k0 = ktile(0) * 64;
#pragma unroll
        for (int n = 0; n < 4; ++n)
            kf[n] = *(const short8*)(Kbase + (size_t)(k0 + n * 16 + lo) * 768 + g * 8);
    }

    for (int it = 0; it < ntiles; ++it) {
        const int k0 = ktile(it) * 64;

        const bool interior =
            (qmax < clen0 && k0 + 63 <= qmin) ||
            (qmin >= clen0 && qmax < cns && k0 >= clen0 && k0 + 63 <= qmin) ||
            (qmin >= cns && k0 + 63 < cns + 32);

        const ushort* V0 = Vbase + k0;
        short8 a00 = *(const short8*)(V0 + (size_t)lo * TPAD + g * 8);
        short8 a01 = *(const short8*)(V0 + (size_t)lo * TPAD + 32 + g * 8);
        short8 a10 = *(const short8*)(V0 + (size_t)(16 + lo) * TPAD + g * 8);
        short8 a11 = *(const short8*)(V0 + (size_t)(16 + lo) * TPAD + 32 + g * 8);

        float pv[4][4];
        float tmax = -1e30f;
#pragma unroll
        for (int n = 0; n < 4; ++n) {
            f32x4 z = {0.f, 0.f, 0.f, 0.f};
            f32x4 sn = __builtin_amdgcn_mfma_f32_16x16x32_bf16(kf[n], qf, z, 0, 0, 0);
            if (interior) {
#pragma unroll
                for (int i = 0; i < 4; ++i) {
                    pv[n][i] = sn[i] * SCL2;
                    tmax = fmaxf(tmax, pv[n][i]);
                }
            } else {
#pragma unroll
                for (int i = 0; i < 4; ++i) {
                    const int k = k0 + n * 16 + g * 4 + i;
                    const bool win = (k >= cns) & (k < cns + 32);
                    bool m;
                    if (q < clen0)         m = (k <= q) | win;
                    else if (q < cns)      m = ((k >= clen0) & (k <= q)) | win;
                    else if (q < cns + 32) m = (k < cns + 32);
                    else                   m = (k < cns + 32) | (k == q);
                    const float sv = m ? sn[i] * SCL2 : -1e30f;
                    pv[n][i] = sv;
                    tmax = fmaxf(tmax, sv);
                }
            }
        }

        short8 kf2[4];
        if (it + 1 < ntiles) {
            const int k1 = ktile(it + 1) * 64;
#pragma unroll
            for (int n = 0; n < 4; ++n)
                kf2[n] = *(const short8*)(Kbase + (size_t)(k1 + n * 16 + lo) * 768 + g * 8);
        }

        tmax = fmaxf(tmax, __shfl_xor(tmax, 16));
        tmax = fmaxf(tmax, __shfl_xor(tmax, 32));
        const float mnew = fmaxf(mrow, tmax);
        if (mnew > mrow) {
            const float scl = exp2f(mrow - mnew);
            srow *= scl;
#pragma unroll
            for (int i = 0; i < 4; ++i) { acc0[i] *= scl; acc1[i] *= scl; }
            mrow = mnew;
        }

        u32 C0[4], C1[4];
        float psum = 0.f;
#pragma unroll
        for (int n = 0; n < 4; ++n) {
            float e0 = (pv[n][0] > -1e29f) ? exp2f(pv[n][0] - mrow) : 0.f;
            float e1 = (pv[n][1] > -1e29f) ? exp2f(pv[n][1] - mrow) : 0.f;
            float e2 = (pv[n][2] > -1e29f) ? exp2f(pv[n][2] - mrow) : 0.f;
            float e3 = (pv[n][3] > -1e29f) ? exp2f(pv[n][3] - mrow) : 0.f;
            psum += (e0 + e1) + (e2 + e3);
            C0[n] = cvtpk(e0, e1);
            C1[n] = cvtpk(e2, e3);
        }
        psum += __shfl_xor(psum, 16);
        psum += __shfl_xor(psum, 32);
        srow += psum;

        short8 pb0, pb1;
        xpose(C0, C1, pb0, pb1);
        acc0 = __builtin_amdgcn_mfma_f32_16x16x32_bf16(a00, pb0, acc0, 0, 0, 0);
        acc0 = __builtin_amdgcn_mfma_f32_16x16x32_bf16(a01, pb1, acc0, 0, 0, 0);
        acc1 = __builtin_amdgcn_mfma_f32_16x16x32_bf16(a10, pb0, acc1, 0, 0, 0);
        acc1 = __builtin_amdgcn_mfma_f32_16x16x32_bf16(a11, pb1, acc1, 0, 0, 0);

#pragma unroll
        for (int n = 0; n < 4; ++n) kf[n] = kf2[n];
    }

    if (q < nv) {
        const float inv = 1.f / fmaxf(srow, 1e-30f);
        ushort* orow = out + (size_t)(base + q) * D + h * HD;
        *(u32*)(orow + g * 4)          = cvtpk(acc0[0] * inv, acc0[1] * inv);
        *(u32*)(orow + g * 4 + 2)      = cvtpk(acc0[2] * inv, acc0[3] * inv);
        *(u32*)(orow + 16 + g * 4)     = cvtpk(acc1[0] * inv, acc1[1] * inv);
        *(u32*)(orow + 16 + g * 4 + 2) = cvtpk(acc1[2] * inv, acc1[3] * inv);
    }
}

extern "C" void kernel_launch(void* const* d_in, const int* in_sizes, int n_in,
                              void* d_out, int out_size, void* d_ws, size_t ws_size,
                              hipStream_t stream)
{
    const float* seq0 = (const float*)d_in[0];
    const float* seq1 = (const float*)d_in[1];
    const int*   len0 = (const int*)d_in[2];
    const int*   len1 = (const int*)d_in[3];
    const float* nst  = (const float*)d_in[4];
    const float* dom  = (const float*)d_in[5];
    const float* cls  = (const float*)d_in[6];
    const float* ln1w = (const float*)d_in[7];
    const float* ln1b = (const float*)d_in[8];
    const float* qkvw = (const float*)d_in[9];
    const float* qkvb = (const float*)d_in[10];
    const float* outw = (const float*)d_in[11];
    const float* outb = (const float*)d_in[12];
    const float* ln2w = (const float*)d_in[13];
    const float* ln2b = (const float*)d_in[14];
    const float* f1w  = (const float*)d_in[15];
    const float* f1b  = (const float*)d_in[16];
    const float* f2w  = (const float*)d_in[17];
    const float* f2b  = (const float*)d_in[18];
    const float* flnw = (const float*)d_in[19];
    const float* flnb = (const float*)d_in[20];

    float*  x   = (float*)d_ws;                         // ROWP*256 f32
    ushort* xn  = (ushort*)(x + (size_t)ROWP * D);      // ROWP*256 bf16
    ushort* big = xn + (size_t)ROWP * D;                // ROWP*1024 bf16 (qkv / ffn hidden)
    ushort* Vt  = big + (size_t)ROWP * HM * D;          // 128*32*832
    ushort* qkvw_t = Vt + (size_t)B * H * TPAD * HD;    // NL*768*256
    ushort* outw_t = qkvw_t + (size_t)NL * 768 * 256;   // NL*256*256
    ushort* f1w_t  = outw_t + (size_t)NL * 256 * 256;   // NL*1024*256
    ushort* f2w_t  = f1w_t  + (size_t)NL * 1024 * 256;  // NL*256*1024

    k_wprep_all<<<3072, 256, 0, stream>>>(qkvw, outw, f1w, f2w,
                                          qkvw_t, outw_t, f1w_t, f2w_t);
    k_build_ln<<<ROWP / 4, 256, 0, stream>>>(seq0, seq1, nst, dom, cls,
                                             ln1w, ln1b, len0, len1, x, xn);

    const int gmm = ROWP / 128;   // 104
    const int gf  = ROWP / 64;    // 208

    for (int l = 0; l < NL; ++l) {
        const bool last = (l == NL - 1);
        // QKV (writes bf16 qkv rows [Q|K|V] into big, compact rows)
        if (!last) {
            k_gemm_mfma<false, true, false><<<dim3(gmm, 6), 256, 0, stream>>>(
                xn, qkvw_t + (size_t)l * 768 * 256, qkvb + (size_t)l * 3 * D, big,
                len0, len1, 3 * D, D, 0);
        } else {
            k_gemm_mfma<false, true, false><<<dim3(gmm, 4), 256, 0, stream>>>(
                xn, qkvw_t + (size_t)l * 768 * 256, qkvb + (size_t)l * 3 * D, big,
                len0, len1, 3 * D, D, 2);
            k_gemm_mfma<false, true, true><<<dim3(B, 2), 256, 0, stream>>>(
                xn, qkvw_t + (size_t)l * 768 * 256, qkvb + (size_t)l * 3 * D, big,
                len0, len1, 3 * D, D, 0);
        }
        k_repack<<<dim3(B * H, 13), 256, 0, stream>>>(big, Vt, len0, len1);
        if (!last)
            k_flash<false><<<dim3(B * H, 13, 4), 64, 0, stream>>>(
                big, Vt, len0, len1, xn);
        else
            k_flash<true><<<dim3(B * H, 1, 4), 64, 0, stream>>>(
                big, Vt, len0, len1, xn);
        // OUT proj + residual + LN2 (fused)
        if (!last)
            k_gemm_fused<0, false><<<gf, 256, 0, stream>>>(
                xn, outw_t + (size_t)l * 256 * 256, outb + (size_t)l * D, x,
                ln2w + l * D, ln2b + l * D, x, xn, nullptr, len0, len1, D);
        else
            k_gemm_fused<0, true><<<B, 256, 0, stream>>>(
                xn, outw_t + (size_t)l * 256 * 256, outb + (size_t)l * D, x,
                ln2w + l * D, ln2b + l * D, x, xn, nullptr, len0, len1, D);
        // FFN1 + GELU
        if (!last)
            k_gemm_mfma<true, true, false><<<dim3(gmm, 8), 256, 0, stream>>>(
                xn, f1w_t + (size_t)l * 1024 * 256, f1b + (size_t)l * HM * D, big,
                len0, len1, HM * D, D, 0);
        else
            k_gemm_mfma<true, true, true><<<dim3(B, 8), 256, 0, stream>>>(
                xn, f1w_t + (size_t)l * 1024 * 256, f1b + (size_t)l * HM * D, big,
                len0, len1, HM * D, D, 0);
        // FFN2 + residual + LN (next layer's LN1, or final LN -> d_out)
        if (!last)
            k_gemm_fused<0, false><<<gf, 256, 0, stream>>>(
                big, f2w_t + (size_t)l * 256 * 1024, f2b + (size_t)l * D, x,
                ln1w + (l + 1) * D, ln1b + (l + 1) * D, x, xn, nullptr,
                len0, len1, HM * D);
        else
            k_gemm_fused<1, true><<<B, 256, 0, stream>>>(
                big, f2w_t + (size_t)l * 256 * 1024, f2b + (size_t)l * D, x,
                flnw, flnb, nullptr, nullptr, (float*)d_out, len0, len1, HM * D);
    }
}

// Round 15
// 458.078 us; speedup vs baseline: 1.1424x; 1.0187x over previous
//
#include <hip/hip_runtime.h>
#include <hip/hip_bf16.h>
#include <math.h>

typedef __attribute__((ext_vector_type(8))) unsigned short ushort8;
typedef __attribute__((ext_vector_type(8))) short short8;
typedef __attribute__((ext_vector_type(4))) float f32x4;
typedef __attribute__((ext_vector_type(4))) unsigned short ushort4v;
typedef __attribute__((ext_vector_type(4))) int i32x4;
typedef unsigned int u32;

namespace {
constexpr int B = 16, L0 = 512, L1 = 256, NS = 32, D = 256, H = 8, NL = 4, HM = 4;
constexpr int T = L0 + L1 + NS + 1;   // 801
constexpr int HD = D / H;             // 32
constexpr int NS_S = L0 + L1;         // 768
constexpr int TPAD = 832;             // 13*64 (fixed per-bh K/V stride)
constexpr int ROWP = 13312;           // 16*832 compact-row capacity
constexpr float EPS = 1e-5f;
constexpr float SCL2  = 0.17677669529663687f * 1.4426950408889634f;  // SCALE*log2e
}

__device__ __forceinline__ ushort f2bf(float f) {
    union { float f; unsigned u; } v; v.f = f;
    return (ushort)((v.u + 0x7fffu + ((v.u >> 16) & 1u)) >> 16);
}

__device__ __forceinline__ u32 cvtpk(float a, float b) {
    u32 r;
    asm("v_cvt_pk_bf16_f32 %0, %1, %2" : "=v"(r) : "v"(a), "v"(b));
    return r;
}

__device__ __forceinline__ void gload_lds16(const void* g, void* l) {
    __builtin_amdgcn_global_load_lds(
        (const __attribute__((address_space(1))) u32*)g,
        (__attribute__((address_space(3))) u32*)l, 16, 0, 0);
}

// compact-row prefix: offset of batch b (64-aligned caps); b=16 -> total rows
__device__ __forceinline__ int offs_of(const int* __restrict__ l0,
                                       const int* __restrict__ l1, int b) {
    int acc = 0;
    for (int j = 0; j < b; ++j) acc += ((l0[j] + l1[j] + 96) >> 6) << 6;  // nv+63, nv=len+33
    return acc;
}

// ---------------- unified weight prep: all four W[K][N] f32 -> W^T[N][K] bf16 ----------------
__global__ __launch_bounds__(256) void k_wprep_all(
    const float* __restrict__ qkvw, const float* __restrict__ outw,
    const float* __restrict__ f1w, const float* __restrict__ f2w,
    ushort* __restrict__ qkvt, ushort* __restrict__ outt,
    ushort* __restrict__ f1t, ushort* __restrict__ f2t)
{
    int id = blockIdx.x;
    const float* src; ushort* dst; int K, N;
    if (id < 768)        { src = qkvw; dst = qkvt; K = 256;  N = 768;  }
    else if (id < 1024)  { id -= 768;  src = outw; dst = outt; K = 256; N = 256; }
    else if (id < 2048)  { id -= 1024; src = f1w;  dst = f1t;  K = 256; N = 1024; }
    else                 { id -= 2048; src = f2w;  dst = f2t;  K = 1024; N = 256; }
    const int ktiles = K >> 5, per = ktiles * (N >> 5);
    const int layer = id / per, rem = id % per;
    const int kb = (rem % ktiles) * 32, nb = (rem / ktiles) * 32;
    src += (size_t)layer * K * N; dst += (size_t)layer * K * N;

    __shared__ float t[32][33];
    const int c = threadIdx.x & 31, r8 = threadIdx.x >> 5;
#pragma unroll
    for (int rr = 0; rr < 32; rr += 8)
        t[r8 + rr][c] = src[(size_t)(kb + r8 + rr) * N + nb + c];
    __syncthreads();
#pragma unroll
    for (int rr = 0; rr < 32; rr += 8)
        dst[(size_t)(nb + r8 + rr) * K + kb + c] = f2bf(t[c][r8 + rr]);
}

// ---------------- build compact x + first LN1 fused; padding rows zeroed ----------------
__global__ __launch_bounds__(256) void k_build_ln(
    const float* __restrict__ s0, const float* __restrict__ s1,
    const float* __restrict__ ns, const float* __restrict__ dom,
    const float* __restrict__ cls, const float* __restrict__ lnw,
    const float* __restrict__ lnb, const int* __restrict__ len0,
    const int* __restrict__ len1, float* __restrict__ x, ushort* __restrict__ xn)
{
    const int wid = threadIdx.x >> 6, lane = threadIdx.x & 63;
    const int row = blockIdx.x * 4 + wid;
    if (row >= ROWP) return;
    const int d0 = lane * 4;

    int bsel = -1, t = -1, acc = 0;
    for (int j = 0; j < 16; ++j) {
        const int n0 = len0[j], n1 = len1[j];
        const int nvj = n0 + n1 + 33;
        const int cap = ((nvj + 63) >> 6) << 6;
        if (row < acc + cap) {
            const int loc = row - acc;
            if (loc < nvj)
                t = (loc < n0) ? loc
                  : (loc < n0 + n1) ? (L0 + loc - n0)
                  : (NS_S + loc - n0 - n1);
            bsel = j;
            break;
        }
        acc += cap;
    }
    if (bsel < 0 || t < 0) {
        float4 z = {0.f, 0.f, 0.f, 0.f};
        *(float4*)(x + (size_t)row * D + d0) = z;
        ushort4v z4 = {0, 0, 0, 0};
        *(ushort4v*)(xn + (size_t)row * D + d0) = z4;
        return;
    }
    const int b = bsel;
    float4 v;
    if (t < L0) {
        v = *(const float4*)(s0 + ((size_t)b * L0 + t) * D + d0);
        float4 dm = *(const float4*)(dom + d0);
        v.x += dm.x; v.y += dm.y; v.z += dm.z; v.w += dm.w;
    } else if (t < NS_S) {
        v = *(const float4*)(s1 + ((size_t)b * L1 + (t - L0)) * D + d0);
        float4 dm = *(const float4*)(dom + D + d0);
        v.x += dm.x; v.y += dm.y; v.z += dm.z; v.w += dm.w;
    } else if (t < NS_S + NS) {
        v = *(const float4*)(ns + ((size_t)b * NS + (t - NS_S)) * D + d0);
    } else {
        v = *(const float4*)(cls + d0);
    }
    *(float4*)(x + (size_t)row * D + d0) = v;
    float s  = v.x + v.y + v.z + v.w;
    float ss = v.x * v.x + v.y * v.y + v.z * v.z + v.w * v.w;
#pragma unroll
    for (int o = 32; o; o >>= 1) { s += __shfl_xor(s, o); ss += __shfl_xor(ss, o); }
    const float mean = s * (1.f / D);
    const float var  = ss * (1.f / D) - mean * mean;
    const float r = rsqrtf(var + EPS);
    float4 wv = *(const float4*)(lnw + d0);
    float4 bv = *(const float4*)(lnb + d0);
    ushort4v o4;
    o4[0] = f2bf((v.x - mean) * r * wv.x + bv.x);
    o4[1] = f2bf((v.y - mean) * r * wv.y + bv.y);
    o4[2] = f2bf((v.z - mean) * r * wv.z + bv.z);
    o4[3] = f2bf((v.w - mean) * r * wv.w + bv.w);
    *(ushort4v*)(xn + (size_t)row * D + d0) = o4;
}

// ---------------- bf16 MFMA GEMM 128x128 dbuf on compact rows; CLSW remaps to cls window ----------------
template<bool GELU, bool OBF, bool CLSW>
__global__ __launch_bounds__(256) void k_gemm_mfma(
    const ushort* __restrict__ A, const ushort* __restrict__ Wt,
    const float* __restrict__ bias, void* __restrict__ Cout,
    const int* __restrict__ len0, const int* __restrict__ len1,
    int N, int K, int nOff)
{
    __shared__ ushort As[2][128 * 64];
    __shared__ ushort Bs[2][128 * 64];
    const int tid = threadIdx.x;
    const int lane = tid & 63, w = tid >> 6;
    const int lo = lane & 15, g = lane >> 4;
    const int wr = w >> 1, wc = w & 1;
    int m0;
    if (CLSW) {
        const int bb = blockIdx.x;
        const int clsrow = offs_of(len0, len1, bb) + len0[bb] + len1[bb] + 32;
        m0 = (clsrow >> 7) << 7;
    } else {
        m0 = blockIdx.x * 128;
        if (m0 >= offs_of(len0, len1, 16)) return;
    }
    const int n0 = (blockIdx.y + nOff) * 128;

    f32x4 zero = {0.f, 0.f, 0.f, 0.f};
    f32x4 acc[4][4];
#pragma unroll
    for (int mi = 0; mi < 4; ++mi)
#pragma unroll
        for (int ni = 0; ni < 4; ++ni) acc[mi][ni] = zero;

    const ushort* srcA[4];
    const ushort* srcB[4];
    int ldsOff[4];
#pragma unroll
    for (int i = 0; i < 4; ++i) {
        const int idx16 = (w * 4 + i) * 64 + lane;
        const int row = idx16 >> 3;
        const int scb = ((idx16 & 7) * 16) ^ ((row & 7) << 4);
        srcA[i] = A  + (size_t)(m0 + row) * K + (scb >> 1);
        srcB[i] = Wt + (size_t)(n0 + row) * K + (scb >> 1);
        ldsOff[i] = (w * 4 + i) * 512;
    }

    const int NT = K >> 6;
#pragma unroll
    for (int i = 0; i < 4; ++i) {
        gload_lds16(srcA[i], &As[0][ldsOff[i]]);
        gload_lds16(srcB[i], &Bs[0][ldsOff[i]]);
    }
    asm volatile("s_waitcnt vmcnt(0)");
    __syncthreads();

    for (int t = 0; t < NT; ++t) {
        const int buf = t & 1;
        if (t + 1 < NT) {
            const int nb = buf ^ 1, ko = (t + 1) * 64;
#pragma unroll
            for (int i = 0; i < 4; ++i) {
                gload_lds16(srcA[i] + ko, &As[nb][ldsOff[i]]);
                gload_lds16(srcB[i] + ko, &Bs[nb][ldsOff[i]]);
            }
        }
#pragma unroll
        for (int kk = 0; kk < 2; ++kk) {
            const int kb = (kk * 64 + g * 16) ^ ((lo & 7) << 4);
            short8 af[4], bfr[4];
#pragma unroll
            for (int mi = 0; mi < 4; ++mi)
                af[mi] = *(const short8*)&As[buf][(wr * 64 + mi * 16 + lo) * 64 + (kb >> 1)];
#pragma unroll
            for (int ni = 0; ni < 4; ++ni)
                bfr[ni] = *(const short8*)&Bs[buf][(wc * 64 + ni * 16 + lo) * 64 + (kb >> 1)];
#pragma unroll
            for (int mi = 0; mi < 4; ++mi)
#pragma unroll
                for (int ni = 0; ni < 4; ++ni)
                    acc[mi][ni] = __builtin_amdgcn_mfma_f32_16x16x32_bf16(
                        af[mi], bfr[ni], acc[mi][ni], 0, 0, 0);
        }
        asm volatile("s_waitcnt vmcnt(0)");
        __syncthreads();
    }

    float bv[4];
#pragma unroll
    for (int ni = 0; ni < 4; ++ni) bv[ni] = bias[n0 + wc * 64 + ni * 16 + lo];
#pragma unroll
    for (int mi = 0; mi < 4; ++mi) {
#pragma unroll
        for (int i = 0; i < 4; ++i) {
            const int row = m0 + wr * 64 + mi * 16 + g * 4 + i;
#pragma unroll
            for (int ni = 0; ni < 4; ++ni) {
                const int col = n0 + wc * 64 + ni * 16 + lo;
                float v = acc[mi][ni][i] + bv[ni];
                if (GELU) v = 0.5f * v * (1.0f + erff(v * 0.70710678118654752f));
                if (OBF) ((ushort*)Cout)[(size_t)row * N + col] = f2bf(v);
                else     ((float*)Cout)[(size_t)row * N + col] = v;
            }
        }
    }
}

// ---------------- fused GEMM (BM=64, BN=256) + residual + LayerNorm on compact rows ----------------
template<int MODE, bool CLSW>
__global__ __launch_bounds__(256) void k_gemm_fused(
    const ushort* __restrict__ A, const ushort* __restrict__ Wt,
    const float* __restrict__ bias, const float* __restrict__ res,
    const float* __restrict__ lnw, const float* __restrict__ lnb,
    float* __restrict__ xout, ushort* __restrict__ xnout,
    float* __restrict__ dout, const int* __restrict__ len0,
    const int* __restrict__ len1, int K)
{
    __shared__ ushort As[2][64 * 64];
    __shared__ ushort Bs[2][256 * 64];
    __shared__ float redS[64][4];
    __shared__ float redQ[64][4];
    const int tid = threadIdx.x;
    const int lane = tid & 63, w = tid >> 6;
    const int lo = lane & 15, g = lane >> 4;
    int m0, clsrow = -1, bb = 0;
    if (CLSW) {
        bb = blockIdx.x;
        clsrow = offs_of(len0, len1, bb) + len0[bb] + len1[bb] + 32;
        m0 = (clsrow >> 6) << 6;
    } else {
        m0 = blockIdx.x * 64;
        if (m0 >= offs_of(len0, len1, 16)) return;
    }

    f32x4 zero = {0.f, 0.f, 0.f, 0.f};
    f32x4 acc[4][4];
#pragma unroll
    for (int mi = 0; mi < 4; ++mi)
#pragma unroll
        for (int ni = 0; ni < 4; ++ni) acc[mi][ni] = zero;

    const ushort* srcA[2]; int ldsOffA[2];
    const ushort* srcB[8]; int ldsOffB[8];
#pragma unroll
    for (int j = 0; j < 2; ++j) {
        const int idx16 = j * 256 + tid;
        const int row = idx16 >> 3;
        const int scb = ((idx16 & 7) * 16) ^ ((row & 7) << 4);
        srcA[j] = A + (size_t)(m0 + row) * K + (scb >> 1);
        ldsOffA[j] = idx16 * 8;
    }
#pragma unroll
    for (int j = 0; j < 8; ++j) {
        const int idx16 = j * 256 + tid;
        const int row = idx16 >> 3;
        const int scb = ((idx16 & 7) * 16) ^ ((row & 7) << 4);
        srcB[j] = Wt + (size_t)row * K + (scb >> 1);
        ldsOffB[j] = idx16 * 8;
    }

    const int NT = K >> 6;
#pragma unroll
    for (int j = 0; j < 2; ++j) gload_lds16(srcA[j], &As[0][ldsOffA[j]]);
#pragma unroll
    for (int j = 0; j < 8; ++j) gload_lds16(srcB[j], &Bs[0][ldsOffB[j]]);
    asm volatile("s_waitcnt vmcnt(0)");
    __syncthreads();

    for (int t = 0; t < NT; ++t) {
        const int buf = t & 1;
        if (t + 1 < NT) {
            const int nb = buf ^ 1, ko = (t + 1) * 64;
#pragma unroll
            for (int j = 0; j < 2; ++j) gload_lds16(srcA[j] + ko, &As[nb][ldsOffA[j]]);
#pragma unroll
            for (int j = 0; j < 8; ++j) gload_lds16(srcB[j] + ko, &Bs[nb][ldsOffB[j]]);
        }
#pragma unroll
        for (int kk = 0; kk < 2; ++kk) {
            const int kb = (kk * 64 + g * 16) ^ ((lo & 7) << 4);
            short8 af[4], bfr[4];
#pragma unroll
            for (int mi = 0; mi < 4; ++mi)
                af[mi] = *(const short8*)&As[buf][(mi * 16 + lo) * 64 + (kb >> 1)];
#pragma unroll
            for (int ni = 0; ni < 4; ++ni)
                bfr[ni] = *(const short8*)&Bs[buf][(w * 64 + ni * 16 + lo) * 64 + (kb >> 1)];
#pragma unroll
            for (int mi = 0; mi < 4; ++mi)
#pragma unroll
                for (int ni = 0; ni < 4; ++ni)
                    acc[mi][ni] = __builtin_amdgcn_mfma_f32_16x16x32_bf16(
                        af[mi], bfr[ni], acc[mi][ni], 0, 0, 0);
        }
        asm volatile("s_waitcnt vmcnt(0)");
        __syncthreads();
    }

    float bv[4], lw[4], lb[4];
#pragma unroll
    for (int ni = 0; ni < 4; ++ni) {
        const int c = w * 64 + ni * 16 + lo;
        bv[ni] = bias[c]; lw[ni] = lnw[c]; lb[ni] = lnb[c];
    }
#pragma unroll
    for (int mi = 0; mi < 4; ++mi) {
#pragma unroll
        for (int i = 0; i < 4; ++i) {
            const int r64 = mi * 16 + g * 4 + i;
            const int row = m0 + r64;
            float s = 0.f, q = 0.f;
#pragma unroll
            for (int ni = 0; ni < 4; ++ni) {
                const int col = w * 64 + ni * 16 + lo;
                float v = acc[mi][ni][i] + bv[ni] + res[(size_t)row * 256 + col];
                acc[mi][ni][i] = v;
                s += v; q += v * v;
            }
            s += __shfl_xor(s, 1); q += __shfl_xor(q, 1);
            s += __shfl_xor(s, 2); q += __shfl_xor(q, 2);
            s += __shfl_xor(s, 4); q += __shfl_xor(q, 4);
            s += __shfl_xor(s, 8); q += __shfl_xor(q, 8);
            if (lo == 0) { redS[r64][w] = s; redQ[r64][w] = q; }
        }
    }
    __syncthreads();
#pragma unroll
    for (int mi = 0; mi < 4; ++mi) {
#pragma unroll
        for (int i = 0; i < 4; ++i) {
            const int r64 = mi * 16 + g * 4 + i;
            const int row = m0 + r64;
            const float S = redS[r64][0] + redS[r64][1] + redS[r64][2] + redS[r64][3];
            const float Q = redQ[r64][0] + redQ[r64][1] + redQ[r64][2] + redQ[r64][3];
            const float mean = S * (1.f / 256.f);
            const float var  = Q * (1.f / 256.f) - mean * mean;
            const float rstd = rsqrtf(var + EPS);
            if (MODE == 0) {
#pragma unroll
                for (int ni = 0; ni < 4; ++ni) {
                    const int col = w * 64 + ni * 16 + lo;
                    const float v = acc[mi][ni][i];
                    xout[(size_t)row * 256 + col] = v;
                    xnout[(size_t)row * 256 + col] = f2bf((v - mean) * rstd * lw[ni] + lb[ni]);
                }
            } else {
                if (row == clsrow) {
#pragma unroll
                    for (int ni = 0; ni < 4; ++ni) {
                        const int col = w * 64 + ni * 16 + lo;
                        dout[(size_t)bb * 256 + col] =
                            (acc[mi][ni][i] - mean) * rstd * lw[ni] + lb[ni];
                    }
                }
            }
        }
    }
}

// ---------------- repack compact K,V -> Kb[bh][832][32], Vt[bh][32][832] ----------------
__global__ __launch_bounds__(256) void k_repack(
    const ushort* __restrict__ qkv, ushort* __restrict__ Kb, ushort* __restrict__ Vt,
    const int* __restrict__ len0, const int* __restrict__ len1)
{
    const int bh = blockIdx.x, tt = blockIdx.y;
    const int b = bh >> 3, h = bh & 7;
    const int nv = len0[b] + len1[b] + 33;
    const int t0 = tt * 64;
    if (t0 >= nv) return;
    const int base = offs_of(len0, len1, b);
    const int tid = threadIdx.x;
    const int r = tid >> 2, c = tid & 3;
    __shared__ ushort vtile[64][40];
    const ushort* kp = qkv + (size_t)(base + t0 + r) * 768 + 256 + h * HD + c * 8;
    ushort8 k8 = *(const ushort8*)kp;
    ushort8 v8 = *(const ushort8*)(kp + 256);
    *(ushort8*)(Kb + ((size_t)bh * TPAD + t0 + r) * HD + c * 8) = k8;
    *(ushort8*)&vtile[r][c * 8] = v8;
    __syncthreads();
    const int d = tid >> 3, cc = tid & 7;
    ushort8 o;
#pragma unroll
    for (int j = 0; j < 8; ++j) o[j] = vtile[cc * 8 + j][d];
    *(ushort8*)(Vt + ((size_t)bh * HD + d) * TPAD + t0 + cc * 8) = o;
}

// ---------------- flash attention: 1-wave blocks, single-tile loop, interior fast-path ----------------
template<bool CLSONLY>
__global__ __launch_bounds__(64) void k_flash(
    const ushort* __restrict__ qkv, const ushort* __restrict__ Kb,
    const ushort* __restrict__ Vt, const int* __restrict__ len0,
    const int* __restrict__ len1, ushort* __restrict__ out)
{
    const int bh = blockIdx.x;
    const int b = bh >> 3, h = bh & 7;
    const int clen0 = len0[b], cns = clen0 + len1[b];
    const int nv = cns + 33;
    const int tl = (nv - 1) >> 6, tn0 = cns >> 6;
    int qt;
    if (CLSONLY) qt = tl;
    else { qt = 12 - (int)blockIdx.y; if (qt > tl) return; }

    const int base = offs_of(len0, len1, b);
    const int w = blockIdx.z;            // 0..3: quarter of q-tile (independent wave)
    const int lane = threadIdx.x;
    const int lo = lane & 15, g = lane >> 4;
    const int b4 = g & 1, b5 = g >> 1;
    const int q0t = qt * 64;
    const int qmin = q0t + w * 16, qmax = qmin + 15;
    const int q = qmin + lo;

    short8 qf = *(const short8*)(qkv + (size_t)(base + q) * 768 + h * HD + g * 8);

    const ushort* Kbase = Kb + (size_t)bh * TPAD * HD;
    const ushort* Vbase = Vt + (size_t)bh * HD * TPAD;

    f32x4 acc0 = {0.f, 0.f, 0.f, 0.f}, acc1 = {0.f, 0.f, 0.f, 0.f};
    float mrow = -1e30f, srow = 0.f;

    const int kts = (qmin >= clen0 && qmax < cns) ? (clen0 >> 6) : 0;
    const int nc = qt - kts + 1;
    const int estart = (qt + 1 > tn0) ? (qt + 1) : tn0;
    const int extra = (tl >= estart) ? (tl - estart + 1) : 0;
    const int ntiles = nc + extra;
    auto ktile = [&](int it) { return (it < nc) ? (kts + it) : (estart + (it - nc)); };

    auto xpose = [&](const u32 C0[4], const u32 C1[4], short8& pb0, short8& pb1) {
        u32 pb0u[4], pb1u[4];
#pragma unroll
        for (int n = 0; n < 4; ++n) {
            const u32 F0 = (u32)__shfl_xor((int)C0[n], 16);
            const u32 F1 = (u32)__shfl_xor((int)C1[n], 16);
            const u32 G00 = b4 ? F0 : C0[n];
            const u32 G01 = b4 ? C0[n] : F0;
            const u32 G10 = b4 ? F1 : C1[n];
            const u32 G11 = b4 ? C1[n] : F1;
            const u32 H00 = (u32)__shfl_xor((int)G00, 32);
            const u32 H01 = (u32)__shfl_xor((int)G01, 32);
            const u32 H10 = (u32)__shfl_xor((int)G10, 32);
            const u32 H11 = (u32)__shfl_xor((int)G11, 32);
            const bool keep = (b5 == b4);
            const u32 S00 = keep ? G00 : H00;
            const u32 S01 = keep ? G01 : H01;
            const u32 S10 = keep ? G10 : H10;
            const u32 S11 = keep ? G11 : H11;
            const bool take = (b5 == (n & 1));
            if ((n >> 1) == 0) {
                pb0u[0] = take ? S00 : pb0u[0];
                pb0u[1] = take ? S10 : pb0u[1];
                pb0u[2] = take ? S01 : pb0u[2];
                pb0u[3] = take ? S11 : pb0u[3];
            } else {
                pb1u[0] = take ? S00 : pb1u[0];
                pb1u[1] = take ? S10 : pb1u[1];
                pb1u[2] = take ? S01 : pb1u[2];
                pb1u[3] = take ? S11 : pb1u[3];
            }
        }
        i32x4 t0 = { (int)pb0u[0], (int)pb0u[1], (int)pb0u[2], (int)pb0u[3] };
        i32x4 t1 = { (int)pb1u[0], (int)pb1u[1], (int)pb1u[2], (int)pb1u[3] };
        pb0 = __builtin_bit_cast(short8, t0);
        pb1 = __builtin_bit_cast(short8, t1);
    };

    short8 kf[4];
    {
        const int k0 = ktile(0) * 64;
#pragma unroll
        for (int n = 0; n < 4; ++n)
            kf[n] = *(const short8*)(Kbase + (size_t)(k0 + n * 16 + lo) * HD + g * 8);
    }

    for (int it = 0; it < ntiles; ++it) {
        const int k0 = ktile(it) * 64;

        const bool interior =
            (qmax < clen0 && k0 + 63 <= qmin) ||
            (qmin >= clen0 && qmax < cns && k0 >= clen0 && k0 + 63 <= qmin) ||
            (qmin >= cns && k0 + 63 < cns + 32);

        const ushort* V0 = Vbase + k0;
        short8 a00 = *(const short8*)(V0 + (size_t)lo * TPAD + g * 8);
        short8 a01 = *(const short8*)(V0 + (size_t)lo * TPAD + 32 + g * 8);
        short8 a10 = *(const short8*)(V0 + (size_t)(16 + lo) * TPAD + g * 8);
        short8 a11 = *(const short8*)(V0 + (size_t)(16 + lo) * TPAD + 32 + g * 8);

        float pv[4][4];
        float tmax = -1e30f;
#pragma unroll
        for (int n = 0; n < 4; ++n) {
            f32x4 z = {0.f, 0.f, 0.f, 0.f};
            f32x4 sn = __builtin_amdgcn_mfma_f32_16x16x32_bf16(kf[n], qf, z, 0, 0, 0);
            if (interior) {
#pragma unroll
                for (int i = 0; i < 4; ++i) {
                    pv[n][i] = sn[i] * SCL2;
                    tmax = fmaxf(tmax, pv[n][i]);
                }
            } else {
#pragma unroll
                for (int i = 0; i < 4; ++i) {
                    const int k = k0 + n * 16 + g * 4 + i;
                    const bool win = (k >= cns) & (k < cns + 32);
                    bool m;
                    if (q < clen0)         m = (k <= q) | win;
                    else if (q < cns)      m = ((k >= clen0) & (k <= q)) | win;
                    else if (q < cns + 32) m = (k < cns + 32);
                    else                   m = (k < cns + 32) | (k == q);
                    const float sv = m ? sn[i] * SCL2 : -1e30f;
                    pv[n][i] = sv;
                    tmax = fmaxf(tmax, sv);
                }
            }
        }

        short8 kf2[4];
        if (it + 1 < ntiles) {
            const int k1 = ktile(it + 1) * 64;
#pragma unroll
            for (int n = 0; n < 4; ++n)
                kf2[n] = *(const short8*)(Kbase + (size_t)(k1 + n * 16 + lo) * HD + g * 8);
        }

        tmax = fmaxf(tmax, __shfl_xor(tmax, 16));
        tmax = fmaxf(tmax, __shfl_xor(tmax, 32));
        const float mnew = fmaxf(mrow, tmax);
        if (mnew > mrow) {
            const float scl = exp2f(mrow - mnew);
            srow *= scl;
#pragma unroll
            for (int i = 0; i < 4; ++i) { acc0[i] *= scl; acc1[i] *= scl; }
            mrow = mnew;
        }

        u32 C0[4], C1[4];
        float psum = 0.f;
#pragma unroll
        for (int n = 0; n < 4; ++n) {
            float e0 = (pv[n][0] > -1e29f) ? exp2f(pv[n][0] - mrow) : 0.f;
            float e1 = (pv[n][1] > -1e29f) ? exp2f(pv[n][1] - mrow) : 0.f;
            float e2 = (pv[n][2] > -1e29f) ? exp2f(pv[n][2] - mrow) : 0.f;
            float e3 = (pv[n][3] > -1e29f) ? exp2f(pv[n][3] - mrow) : 0.f;
            psum += (e0 + e1) + (e2 + e3);
            C0[n] = cvtpk(e0, e1);
            C1[n] = cvtpk(e2, e3);
        }
        psum += __shfl_xor(psum, 16);
        psum += __shfl_xor(psum, 32);
        srow += psum;

        short8 pb0, pb1;
        xpose(C0, C1, pb0, pb1);
        acc0 = __builtin_amdgcn_mfma_f32_16x16x32_bf16(a00, pb0, acc0, 0, 0, 0);
        acc0 = __builtin_amdgcn_mfma_f32_16x16x32_bf16(a01, pb1, acc0, 0, 0, 0);
        acc1 = __builtin_amdgcn_mfma_f32_16x16x32_bf16(a10, pb0, acc1, 0, 0, 0);
        acc1 = __builtin_amdgcn_mfma_f32_16x16x32_bf16(a11, pb1, acc1, 0, 0, 0);

#pragma unroll
        for (int n = 0; n < 4; ++n) kf[n] = kf2[n];
    }

    if (q < nv) {
        const float inv = 1.f / fmaxf(srow, 1e-30f);
        ushort* orow = out + (size_t)(base + q) * D + h * HD;
        *(u32*)(orow + g * 4)          = cvtpk(acc0[0] * inv, acc0[1] * inv);
        *(u32*)(orow + g * 4 + 2)      = cvtpk(acc0[2] * inv, acc0[3] * inv);
        *(u32*)(orow + 16 + g * 4)     = cvtpk(acc1[0] * inv, acc1[1] * inv);
        *(u32*)(orow + 16 + g * 4 + 2) = cvtpk(acc1[2] * inv, acc1[3] * inv);
    }
}

extern "C" void kernel_launch(void* const* d_in, const int* in_sizes, int n_in,
                              void* d_out, int out_size, void* d_ws, size_t ws_size,
                              hipStream_t stream)
{
    const float* seq0 = (const float*)d_in[0];
    const float* seq1 = (const float*)d_in[1];
    const int*   len0 = (const int*)d_in[2];
    const int*   len1 = (const int*)d_in[3];
    const float* nst  = (const float*)d_in[4];
    const float* dom  = (const float*)d_in[5];
    const float* cls  = (const float*)d_in[6];
    const float* ln1w = (const float*)d_in[7];
    const float* ln1b = (const float*)d_in[8];
    const float* qkvw = (const float*)d_in[9];
    const float* qkvb = (const float*)d_in[10];
    const float* outw = (const float*)d_in[11];
    const float* outb = (const float*)d_in[12];
    const float* ln2w = (const float*)d_in[13];
    const float* ln2b = (const float*)d_in[14];
    const float* f1w  = (const float*)d_in[15];
    const float* f1b  = (const float*)d_in[16];
    const float* f2w  = (const float*)d_in[17];
    const float* f2b  = (const float*)d_in[18];
    const float* flnw = (const float*)d_in[19];
    const float* flnb = (const float*)d_in[20];

    float*  x   = (float*)d_ws;                         // ROWP*256 f32
    ushort* xn  = (ushort*)(x + (size_t)ROWP * D);      // ROWP*256 bf16
    ushort* big = xn + (size_t)ROWP * D;                // ROWP*1024 bf16 (qkv / ffn hidden)
    ushort* Kb  = big + (size_t)ROWP * HM * D;          // 128*832*32
    ushort* Vt  = Kb + (size_t)B * H * TPAD * HD;       // 128*32*832
    ushort* qkvw_t = Vt + (size_t)B * H * TPAD * HD;    // NL*768*256
    ushort* outw_t = qkvw_t + (size_t)NL * 768 * 256;   // NL*256*256
    ushort* f1w_t  = outw_t + (size_t)NL * 256 * 256;   // NL*1024*256
    ushort* f2w_t  = f1w_t  + (size_t)NL * 1024 * 256;  // NL*256*1024

    k_wprep_all<<<3072, 256, 0, stream>>>(qkvw, outw, f1w, f2w,
                                          qkvw_t, outw_t, f1w_t, f2w_t);
    k_build_ln<<<ROWP / 4, 256, 0, stream>>>(seq0, seq1, nst, dom, cls,
                                             ln1w, ln1b, len0, len1, x, xn);

    const int gmm = ROWP / 128;   // 104
    const int gf  = ROWP / 64;    // 208

    for (int l = 0; l < NL; ++l) {
        const bool last = (l == NL - 1);
        // QKV (writes bf16 qkv rows [Q|K|V] into big, compact rows)
        if (!last) {
            k_gemm_mfma<false, true, false><<<dim3(gmm, 6), 256, 0, stream>>>(
                xn, qkvw_t + (size_t)l * 768 * 256, qkvb + (size_t)l * 3 * D, big,
                len0, len1, 3 * D, D, 0);
        } else {
            k_gemm_mfma<false, true, false><<<dim3(gmm, 4), 256, 0, stream>>>(
                xn, qkvw_t + (size_t)l * 768 * 256, qkvb + (size_t)l * 3 * D, big,
                len0, len1, 3 * D, D, 2);
            k_gemm_mfma<false, true, true><<<dim3(B, 2), 256, 0, stream>>>(
                xn, qkvw_t + (size_t)l * 768 * 256, qkvb + (size_t)l * 3 * D, big,
                len0, len1, 3 * D, D, 0);
        }
        k_repack<<<dim3(B * H, 13), 256, 0, stream>>>(big, Kb, Vt, len0, len1);
        if (!last)
            k_flash<false><<<dim3(B * H, 13, 4), 64, 0, stream>>>(
                big, Kb, Vt, len0, len1, xn);
        else
            k_flash<true><<<dim3(B * H, 1, 4), 64, 0, stream>>>(
                big, Kb, Vt, len0, len1, xn);
        // OUT proj + residual + LN2 (fused)
        if (!last)
            k_gemm_fused<0, false><<<gf, 256, 0, stream>>>(
                xn, outw_t + (size_t)l * 256 * 256, outb + (size_t)l * D, x,
                ln2w + l * D, ln2b + l * D, x, xn, nullptr, len0, len1, D);
        else
            k_gemm_fused<0, true><<<B, 256, 0, stream>>>(
                xn, outw_t + (size_t)l * 256 * 256, outb + (size_t)l * D, x,
                ln2w + l * D, ln2b + l * D, x, xn, nullptr, len0, len1, D);
        // FFN1 + GELU
        if (!last)
            k_gemm_mfma<true, true, false><<<dim3(gmm, 8), 256, 0, stream>>>(
                xn, f1w_t + (size_t)l * 1024 * 256, f1b + (size_t)l * HM * D, big,
                len0, len1, HM * D, D, 0);
        else
            k_gemm_mfma<true, true, true><<<dim3(B, 8), 256, 0, stream>>>(
                xn, f1w_t + (size_t)l * 1024 * 256, f1b + (size_t)l * HM * D, big,
                len0, len1, HM * D, D, 0);
        // FFN2 + residual + LN (next layer's LN1, or final LN -> d_out)
        if (!last)
            k_gemm_fused<0, false><<<gf, 256, 0, stream>>>(
                big, f2w_t + (size_t)l * 256 * 1024, f2b + (size_t)l * D, x,
                ln1w + (l + 1) * D, ln1b + (l + 1) * D, x, xn, nullptr,
                len0, len1, HM * D);
        else
            k_gemm_fused<1, true><<<B, 256, 0, stream>>>(
                big, f2w_t + (size_t)l * 256 * 1024, f2b + (size_t)l * D, x,
                flnw, flnb, nullptr, nullptr, (float*)d_out, len0, len1, HM * D);
    }
}